// Round 12
// baseline (155.920 us; speedup 1.0000x reference)
//
#include <hip/hip_runtime.h>

#define F 128
#define SCANB 1024
#define NBLK 128        // hist/scatter width == mat columns
#define BSHIFT 6        // 64 nodes per bucket
#define MAXNB 4096      // nb guard (scan_b / lbase capacity)
#define CAP 4096        // per-bucket LDS edge capacity
#define SMEM_BYTES 43264  // wt(34816) + xs[4][4][132](8448)

typedef __attribute__((ext_vector_type(8))) short short8;
typedef __attribute__((ext_vector_type(4))) float f32x4;

static __device__ __forceinline__ short f2bf(float f) {
    union { float f; unsigned u; } v; v.f = f;
    unsigned r = v.u + 0x7FFF + ((v.u >> 16) & 1);   // round-to-nearest-even
    return (short)(r >> 16);
}
static __device__ __forceinline__ float bf_lo(unsigned u) {
    return __builtin_bit_cast(float, u << 16);
}
static __device__ __forceinline__ float bf_hi(unsigned u) {
    return __builtin_bit_cast(float, u & 0xFFFF0000u);
}
static __device__ __forceinline__ uint4 pack8(float a0,float a1,float a2,float a3,
                                              float a4,float a5,float a6,float a7) {
    uint4 o;
    o.x = ((unsigned)(unsigned short)f2bf(a1) << 16) | (unsigned short)f2bf(a0);
    o.y = ((unsigned)(unsigned short)f2bf(a3) << 16) | (unsigned short)f2bf(a2);
    o.z = ((unsigned)(unsigned short)f2bf(a5) << 16) | (unsigned short)f2bf(a4);
    o.w = ((unsigned)(unsigned short)f2bf(a7) << 16) | (unsigned short)f2bf(a6);
    return o;
}

// ========== role-split kernel: blocks<hblk do dst-hist, rest do hW GEMM ====
__global__ __launch_bounds__(256) void k_gemm_hist(
    const float* __restrict__ h, const float* __restrict__ w,
    unsigned* __restrict__ hb, const int* __restrict__ dst,
    int* __restrict__ mat, int n_nodes, int n_edges, int nb, int hblk) {
    __shared__ alignas(16) char smem[SMEM_BYTES];
    const int tid = threadIdx.x;
    const int bid = blockIdx.x;

    if (bid < hblk) {
        // ---- histogram role ----
        int* lh = (int*)smem;
        for (int i = tid; i < nb; i += 256) lh[i] = 0;
        __syncthreads();
        const int epb = (n_edges + hblk - 1) / hblk;
        const int e0 = bid * epb, e1 = min(e0 + epb, n_edges);
        for (int e = e0 + tid; e < e1; e += 256)
            atomicAdd(&lh[dst[e] >> BSHIFT], 1);
        __syncthreads();
        for (int i = tid; i < nb; i += 256)
            mat[(size_t)i * NBLK + bid] = lh[i];
        return;
    }

    // ---- GEMM role: rows [base, base+64) ----
    short* wt = (short*)smem;               // [128*136] bf16 W^T  (34816 B)
    float* xs = (float*)(smem + 34816);     // [4][4][132] per-wave C bounce
    {
        int n = tid & 127;
        for (int k = tid >> 7; k < 128; k += 2)
            wt[n * 136 + k] = f2bf(w[(size_t)k * 128 + n]);
    }
    __syncthreads();

    const int wv = tid >> 6, l = tid & 63, lr = l & 15, lk = l >> 4, q = l & 15;
    const int base = (bid - hblk) * 64;
    if (base >= n_nodes) return;
    const int row = base + wv * 16 + lr;
    const bool valid = row < n_nodes;

    short8 af[4];
    #pragma unroll
    for (int kk = 0; kk < 4; ++kk) {
        int k0 = kk * 32 + lk * 8;
        float4 a0{0,0,0,0}, a1{0,0,0,0};
        if (valid) {
            a0 = *(const float4*)(h + (size_t)row * F + k0);
            a1 = *(const float4*)(h + (size_t)row * F + k0 + 4);
        }
        af[kk] = short8{ f2bf(a0.x), f2bf(a0.y), f2bf(a0.z), f2bf(a0.w),
                         f2bf(a1.x), f2bf(a1.y), f2bf(a1.z), f2bf(a1.w) };
    }
    f32x4 acc[8];
    #pragma unroll
    for (int n = 0; n < 8; ++n) acc[n] = f32x4{0, 0, 0, 0};
    #pragma unroll
    for (int kk = 0; kk < 4; ++kk) {
        const int kb = kk * 32 + lk * 8;
        #pragma unroll
        for (int n = 0; n < 8; ++n) {
            short8 bfr = *(const short8*)(&wt[(n * 16 + lr) * 136 + kb]);
            acc[n] = __builtin_amdgcn_mfma_f32_16x16x32_bf16(af[kk], bfr, acc[n], 0, 0, 0);
        }
    }
    // per-r bounce: row lk*4+r lives in LDS slot lk
    float* xw = xs + wv * (4 * 132);
    #pragma unroll
    for (int r = 0; r < 4; ++r) {
        #pragma unroll
        for (int n = 0; n < 8; ++n)
            xw[lk * 132 + n * 16 + lr] = acc[n][r];
        int grow = base + wv * 16 + lk * 4 + r;
        float4 a = *(const float4*)&xw[lk * 132 + q * 8];
        float4 b = *(const float4*)&xw[lk * 132 + q * 8 + 4];
        uint4 o = pack8(a.x, a.y, a.z, a.w, b.x, b.y, b.z, b.w);
        if (grow < n_nodes)
            ((uint4*)hb)[(size_t)grow * 16 + q] = o;
    }
}

// ========== exclusive scan (chunked; bsum holds per-chunk totals) ==========
__global__ __launch_bounds__(SCANB) void k_scan_a(const int* in, int* out,
                                                  int* bsum, int n) {
    __shared__ int tmp[SCANB];
    int i = blockIdx.x * SCANB + threadIdx.x;
    int v = (i < n) ? in[i] : 0;
    tmp[threadIdx.x] = v;
    __syncthreads();
    for (int off = 1; off < SCANB; off <<= 1) {
        int t = (threadIdx.x >= off) ? tmp[threadIdx.x - off] : 0;
        __syncthreads();
        tmp[threadIdx.x] += t;
        __syncthreads();
    }
    if (i < n) out[i] = tmp[threadIdx.x] - v;
    if (threadIdx.x == SCANB - 1) bsum[blockIdx.x] = tmp[SCANB - 1];
}

__global__ __launch_bounds__(512) void k_scan_b(int* bsum, int nb) {
    __shared__ int tmp[512];
    int i = threadIdx.x;
    int v = (i < nb) ? bsum[i] : 0;
    tmp[i] = v;
    __syncthreads();
    for (int off = 1; off < 512; off <<= 1) {
        int t = (i >= off) ? tmp[i - off] : 0;
        __syncthreads();
        tmp[i] += t;
        __syncthreads();
    }
    if (i < nb) bsum[i] = tmp[i] - v;
}

__global__ __launch_bounds__(SCANB) void k_scan_c(int* out, const int* bsum, int n) {
    int i = blockIdx.x * SCANB + threadIdx.x;
    if (i < n) out[i] += bsum[blockIdx.x];
}

// ========== binned scatter; scan_c folded in via bsum lookup ===============
__global__ __launch_bounds__(256) void k_part_scatter(
    const int* __restrict__ src, const int* __restrict__ dst,
    const int* __restrict__ mat, const int* __restrict__ bsum,
    unsigned* __restrict__ binned, int n_edges, int nb, int epb) {
    __shared__ int lbase[MAXNB];
    const int bid = blockIdx.x;
    for (int i = threadIdx.x; i < nb; i += 256) {
        int idx = i * NBLK + bid;
        lbase[i] = mat[idx] + bsum[idx >> 10];
    }
    __syncthreads();
    int e0 = bid * epb;
    int e1 = min(e0 + epb, n_edges);
    for (int e = e0 + threadIdx.x; e < e1; e += 256) {
        int d = dst[e];
        int b = d >> BSHIFT;
        int pos = atomicAdd(&lbase[b], 1);   // LDS atomic only
        binned[pos] = ((unsigned)(d & ((1 << BSHIFT) - 1)) << 26) | (unsigned)src[e];
    }
}

// ========== FUSED: per-bucket CSR (in LDS) + gather + LN + ReLU ============
// One block per bucket. Phase 1: build local CSR in LDS (lesrc, cap 4096;
// spills to global esrc if a bucket overflows). Phase 2: 4 waves x 16 nodes
// wide-gather from hb with LN/ReLU epilogue.
__global__ __launch_bounds__(256) void k_csr_gather(
    const unsigned* __restrict__ binned, const int* __restrict__ mat,
    const int* __restrict__ bsum, const unsigned* __restrict__ hb,
    const float* __restrict__ bias, const float* __restrict__ gamma,
    const float* __restrict__ beta, int* __restrict__ esrc,
    float* __restrict__ out, int n_edges, int n_nodes, int nb) {
    __shared__ int ldeg[64], loffs[64], lcur[64];
    __shared__ int lesrc[CAP];

    const int tid = threadIdx.x;
    const int b = blockIdx.x;
    const int i0 = b * NBLK;
    const int start = mat[i0] + bsum[i0 >> 10];
    int end = n_edges;
    if (b + 1 < nb) {
        int i1 = (b + 1) * NBLK;
        end = mat[i1] + bsum[i1 >> 10];
    }
    const int cnt = end - start;
    const int base_node = b << BSHIFT;
    const int nn = min(1 << BSHIFT, n_nodes - base_node);

    for (int i = tid; i < 64; i += 256) { ldeg[i] = 0; lcur[i] = 0; }
    __syncthreads();
    for (int i = tid; i < cnt; i += 256)
        atomicAdd(&ldeg[binned[start + i] >> 26], 1);
    __syncthreads();
    if (tid == 0) {
        int run = 0;
        for (int i = 0; i < nn; ++i) { loffs[i] = run; run += ldeg[i]; }
    }
    __syncthreads();

    const bool inLds = cnt <= CAP;
    if (inLds) {
        for (int i = tid; i < cnt; i += 256) {
            unsigned p = binned[start + i];
            int ln = p >> 26;
            int pos = loffs[ln] + atomicAdd(&lcur[ln], 1);
            lesrc[pos] = (int)(p & ((1u << 26) - 1));
        }
    } else {
        for (int i = tid; i < cnt; i += 256) {
            unsigned p = binned[start + i];
            int ln = p >> 26;
            int pos = loffs[ln] + atomicAdd(&lcur[ln], 1);
            esrc[start + pos] = (int)(p & ((1u << 26) - 1));
        }
    }
    __syncthreads();

    // ---- gather phase: wave wv owns nodes [wv*16, wv*16+16) of this bucket
    const int wv = tid >> 6, l = tid & 63, g = l >> 4, q = l & 15;
    const int* ep = inLds ? (const int*)lesrc : (const int*)(esrc + start);

    float4 bs0 = *(const float4*)(bias  + q * 8);
    float4 bs1 = *(const float4*)(bias  + q * 8 + 4);
    float4 gm0 = *(const float4*)(gamma + q * 8);
    float4 gm1 = *(const float4*)(gamma + q * 8 + 4);
    float4 bt0 = *(const float4*)(beta  + q * 8);
    float4 bt1 = *(const float4*)(beta  + q * 8 + 4);

    for (int ni = 0; ni < 16; ++ni) {
        int ln = wv * 16 + ni;
        if (ln >= nn) break;
        const int eb = loffs[ln];
        const int dn = ldeg[ln];

        float a0=0,a1=0,a2=0,a3=0,a4=0,a5=0,a6=0,a7=0;
        int i = 0;
        for (; i + 8 <= dn; i += 8) {
            int s0 = ep[eb + i + g];
            int s1 = ep[eb + i + 4 + g];
            uint4 v0 = *((const uint4*)(hb + (size_t)s0 * 64 + q * 4));
            uint4 v1 = *((const uint4*)(hb + (size_t)s1 * 64 + q * 4));
            a0 += bf_lo(v0.x) + bf_lo(v1.x); a1 += bf_hi(v0.x) + bf_hi(v1.x);
            a2 += bf_lo(v0.y) + bf_lo(v1.y); a3 += bf_hi(v0.y) + bf_hi(v1.y);
            a4 += bf_lo(v0.z) + bf_lo(v1.z); a5 += bf_hi(v0.z) + bf_hi(v1.z);
            a6 += bf_lo(v0.w) + bf_lo(v1.w); a7 += bf_hi(v0.w) + bf_hi(v1.w);
        }
        for (; i < dn; i += 4) {
            int e = i + g;
            if (e < dn) {
                int s = ep[eb + e];
                uint4 v = *((const uint4*)(hb + (size_t)s * 64 + q * 4));
                a0 += bf_lo(v.x); a1 += bf_hi(v.x);
                a2 += bf_lo(v.y); a3 += bf_hi(v.y);
                a4 += bf_lo(v.z); a5 += bf_hi(v.z);
                a6 += bf_lo(v.w); a7 += bf_hi(v.w);
            }
        }
        #pragma unroll
        for (int m = 16; m <= 32; m <<= 1) {
            a0 += __shfl_xor(a0, m); a1 += __shfl_xor(a1, m);
            a2 += __shfl_xor(a2, m); a3 += __shfl_xor(a3, m);
            a4 += __shfl_xor(a4, m); a5 += __shfl_xor(a5, m);
            a6 += __shfl_xor(a6, m); a7 += __shfl_xor(a7, m);
        }
        const float nv = dn > 0 ? 1.0f / (float)dn : 0.0f;
        float f0 = a0 * nv + bs0.x, f1 = a1 * nv + bs0.y;
        float f2 = a2 * nv + bs0.z, f3 = a3 * nv + bs0.w;
        float f4 = a4 * nv + bs1.x, f5 = a5 * nv + bs1.y;
        float f6 = a6 * nv + bs1.z, f7 = a7 * nv + bs1.w;

        float s  = ((f0 + f1) + (f2 + f3)) + ((f4 + f5) + (f6 + f7));
        float q2 = ((f0*f0 + f1*f1) + (f2*f2 + f3*f3)) + ((f4*f4 + f5*f5) + (f6*f6 + f7*f7));
        #pragma unroll
        for (int m = 1; m <= 8; m <<= 1) {
            s  += __shfl_xor(s, m);
            q2 += __shfl_xor(q2, m);
        }
        float mu   = s * (1.0f / F);
        float var  = q2 * (1.0f / F) - mu * mu;
        float rstd = rsqrtf(var + 1e-5f);

        if (g == 0) {
            float4 o0, o1;
            o0.x = fmaxf((f0 - mu) * rstd * gm0.x + bt0.x, 0.0f);
            o0.y = fmaxf((f1 - mu) * rstd * gm0.y + bt0.y, 0.0f);
            o0.z = fmaxf((f2 - mu) * rstd * gm0.z + bt0.z, 0.0f);
            o0.w = fmaxf((f3 - mu) * rstd * gm0.w + bt0.w, 0.0f);
            o1.x = fmaxf((f4 - mu) * rstd * gm1.x + bt1.x, 0.0f);
            o1.y = fmaxf((f5 - mu) * rstd * gm1.y + bt1.y, 0.0f);
            o1.z = fmaxf((f6 - mu) * rstd * gm1.z + bt1.z, 0.0f);
            o1.w = fmaxf((f7 - mu) * rstd * gm1.w + bt1.w, 0.0f);
            float* op = out + (size_t)(base_node + ln) * F + q * 8;
            *(float4*)op = o0;
            *(float4*)(op + 4) = o1;
        }
    }
}

// ========== fallback CSR build (direct, node-level scan) ===================
__global__ __launch_bounds__(256) void k_hist(const int* __restrict__ dst,
                                              int* __restrict__ deg, int n_edges) {
    int e = blockIdx.x * 256 + threadIdx.x;
    if (e < n_edges) atomicAdd(&deg[dst[e]], 1);
}

__global__ __launch_bounds__(256) void k_scatter_idx(
    const int* __restrict__ src, const int* __restrict__ dst,
    const int* __restrict__ offs, int* __restrict__ cursor,
    int* __restrict__ esrc, int n_edges) {
    int e = blockIdx.x * 256 + threadIdx.x;
    if (e >= n_edges) return;
    int d = dst[e];
    int pos = offs[d] + atomicAdd(&cursor[d], 1);
    esrc[pos] = src[e];
}

// ========== standalone gather (fallback path) ==============================
__global__ __launch_bounds__(256) void k_gather_ln(
    const unsigned* __restrict__ hb, const int* __restrict__ esrc,
    const int* __restrict__ offs, const int* __restrict__ deg,
    const float* __restrict__ bias, const float* __restrict__ gamma,
    const float* __restrict__ beta, float* __restrict__ out, int n_nodes) {
    int t = blockIdx.x * 256 + threadIdx.x;
    int node = t >> 6;
    int l = t & 63;
    if (node >= n_nodes) return;
    const int g = l >> 4;
    const int q = l & 15;

    float4 bs0 = *(const float4*)(bias  + q * 8);
    float4 bs1 = *(const float4*)(bias  + q * 8 + 4);
    float4 gm0 = *(const float4*)(gamma + q * 8);
    float4 gm1 = *(const float4*)(gamma + q * 8 + 4);
    float4 bt0 = *(const float4*)(beta  + q * 8);
    float4 bt1 = *(const float4*)(beta  + q * 8 + 4);

    const int start = offs[node];
    const int dn = deg[node];
    const int end = start + dn;

    float a0=0,a1=0,a2=0,a3=0,a4=0,a5=0,a6=0,a7=0;
    int i = start;
    for (; i + 8 <= end; i += 8) {
        int s0 = esrc[i + g];
        int s1 = esrc[i + 4 + g];
        uint4 v0 = *((const uint4*)(hb + (size_t)s0 * 64 + q * 4));
        uint4 v1 = *((const uint4*)(hb + (size_t)s1 * 64 + q * 4));
        a0 += bf_lo(v0.x) + bf_lo(v1.x); a1 += bf_hi(v0.x) + bf_hi(v1.x);
        a2 += bf_lo(v0.y) + bf_lo(v1.y); a3 += bf_hi(v0.y) + bf_hi(v1.y);
        a4 += bf_lo(v0.z) + bf_lo(v1.z); a5 += bf_hi(v0.z) + bf_hi(v1.z);
        a6 += bf_lo(v0.w) + bf_lo(v1.w); a7 += bf_hi(v0.w) + bf_hi(v1.w);
    }
    for (; i < end; i += 4) {
        int e = i + g;
        if (e < end) {
            int s = esrc[e];
            uint4 v = *((const uint4*)(hb + (size_t)s * 64 + q * 4));
            a0 += bf_lo(v.x); a1 += bf_hi(v.x);
            a2 += bf_lo(v.y); a3 += bf_hi(v.y);
            a4 += bf_lo(v.z); a5 += bf_hi(v.z);
            a6 += bf_lo(v.w); a7 += bf_hi(v.w);
        }
    }
    #pragma unroll
    for (int m = 16; m <= 32; m <<= 1) {
        a0 += __shfl_xor(a0, m); a1 += __shfl_xor(a1, m);
        a2 += __shfl_xor(a2, m); a3 += __shfl_xor(a3, m);
        a4 += __shfl_xor(a4, m); a5 += __shfl_xor(a5, m);
        a6 += __shfl_xor(a6, m); a7 += __shfl_xor(a7, m);
    }
    const float nv = dn > 0 ? 1.0f / (float)dn : 0.0f;
    float f0 = a0 * nv + bs0.x, f1 = a1 * nv + bs0.y;
    float f2 = a2 * nv + bs0.z, f3 = a3 * nv + bs0.w;
    float f4 = a4 * nv + bs1.x, f5 = a5 * nv + bs1.y;
    float f6 = a6 * nv + bs1.z, f7 = a7 * nv + bs1.w;

    float s  = ((f0 + f1) + (f2 + f3)) + ((f4 + f5) + (f6 + f7));
    float q2 = ((f0*f0 + f1*f1) + (f2*f2 + f3*f3)) + ((f4*f4 + f5*f5) + (f6*f6 + f7*f7));
    #pragma unroll
    for (int m = 1; m <= 8; m <<= 1) {
        s  += __shfl_xor(s, m);
        q2 += __shfl_xor(q2, m);
    }
    float mu   = s * (1.0f / F);
    float var  = q2 * (1.0f / F) - mu * mu;
    float rstd = rsqrtf(var + 1e-5f);

    if (g == 0) {
        float4 o0, o1;
        o0.x = fmaxf((f0 - mu) * rstd * gm0.x + bt0.x, 0.0f);
        o0.y = fmaxf((f1 - mu) * rstd * gm0.y + bt0.y, 0.0f);
        o0.z = fmaxf((f2 - mu) * rstd * gm0.z + bt0.z, 0.0f);
        o0.w = fmaxf((f3 - mu) * rstd * gm0.w + bt0.w, 0.0f);
        o1.x = fmaxf((f4 - mu) * rstd * gm1.x + bt1.x, 0.0f);
        o1.y = fmaxf((f5 - mu) * rstd * gm1.y + bt1.y, 0.0f);
        o1.z = fmaxf((f6 - mu) * rstd * gm1.z + bt1.z, 0.0f);
        o1.w = fmaxf((f7 - mu) * rstd * gm1.w + bt1.w, 0.0f);
        float* op = out + (size_t)node * F + q * 8;
        *(float4*)op = o0;
        *(float4*)(op + 4) = o1;
    }
}

extern "C" void kernel_launch(void* const* d_in, const int* in_sizes, int n_in,
                              void* d_out, int out_size, void* d_ws, size_t ws_size,
                              hipStream_t stream) {
    const float* h      = (const float*)d_in[0];
    const float* weight = (const float*)d_in[1];
    const float* bias   = (const float*)d_in[2];
    const float* gamma  = (const float*)d_in[3];
    const float* beta   = (const float*)d_in[4];
    const int*   src    = (const int*)d_in[5];
    const int*   dst    = (const int*)d_in[6];

    const int n_nodes = in_sizes[0] / F;
    const int n_edges = in_sizes[5];

    float* x = (float*)d_out;

    const int nb = (n_nodes + (1 << BSHIFT) - 1) >> BSHIFT;
    const int len = nb * NBLK;
    const int nscan = (len + SCANB - 1) / SCANB;
    const bool shift_ok = (nb <= MAXNB) && (nscan <= 512) && (n_nodes <= (1 << 26));

    // ws ints: deg[N] | offs[N] | esrc[E] | hb[N*64 u32] | bsum[1024] |
    //          mat[nb*NBLK] | binned[E u32]   (fallback: cursor = mat slot)
    int* deg    = (int*)d_ws;
    int* offs   = deg + n_nodes;
    int* esrc   = offs + n_nodes;
    unsigned* hb = (unsigned*)(esrc + n_edges);
    int* bsum   = (int*)(hb + (size_t)n_nodes * 64);
    int* mat    = bsum + 1024;
    unsigned* binned = (unsigned*)(mat + (size_t)len);
    int* cursor = mat;

    size_t need_common = ((size_t)2 * n_nodes + (size_t)n_edges + 1024) * sizeof(int)
                       + (size_t)n_nodes * 64 * sizeof(unsigned);
    size_t need_new  = need_common + ((size_t)len + (size_t)n_edges) * sizeof(int);
    size_t need_fall = need_common + (size_t)n_nodes * sizeof(int);
    bool use_new = shift_ok && ws_size >= need_new;

    const int gb = (n_nodes + 63) / 64;

    if (use_new) {
        k_gemm_hist<<<NBLK + gb, 256, 0, stream>>>(h, weight, hb, dst, mat,
                                                   n_nodes, n_edges, nb, NBLK);
        k_scan_a<<<nscan, SCANB, 0, stream>>>(mat, mat, bsum, len);
        k_scan_b<<<1, 512, 0, stream>>>(bsum, nscan);
        const int epb = (n_edges + NBLK - 1) / NBLK;
        k_part_scatter<<<NBLK, 256, 0, stream>>>(src, dst, mat, bsum, binned,
                                                 n_edges, nb, epb);
        k_csr_gather<<<nb, 256, 0, stream>>>(binned, mat, bsum, hb,
                                             bias, gamma, beta, esrc, x,
                                             n_edges, n_nodes, nb);
    } else if (ws_size >= need_fall) {
        k_gemm_hist<<<gb, 256, 0, stream>>>(h, weight, hb, dst, mat,
                                            n_nodes, n_edges, nb, 0);
        const int nscan2 = (n_nodes + SCANB - 1) / SCANB;
        hipMemsetAsync(deg, 0, (size_t)n_nodes * sizeof(int), stream);
        hipMemsetAsync(cursor, 0, (size_t)n_nodes * sizeof(int), stream);
        k_hist<<<(n_edges + 255) / 256, 256, 0, stream>>>(dst, deg, n_edges);
        k_scan_a<<<nscan2, SCANB, 0, stream>>>(deg, offs, bsum, n_nodes);
        k_scan_b<<<1, 512, 0, stream>>>(bsum, nscan2);
        k_scan_c<<<nscan2, SCANB, 0, stream>>>(offs, bsum, n_nodes);
        k_scatter_idx<<<(n_edges + 255) / 256, 256, 0, stream>>>(
            src, dst, offs, cursor, esrc, n_edges);
        int gblocks = (int)(((size_t)n_nodes * 64 + 255) / 256);
        k_gather_ln<<<gblocks, 256, 0, stream>>>(hb, esrc, offs, deg,
                                                 bias, gamma, beta, x, n_nodes);
    }
}

// Round 13
// 144.503 us; speedup vs baseline: 1.0790x; 1.0790x over previous
//
#include <hip/hip_runtime.h>

#define F 128
#define SCANB 1024
#define NBLK 128        // hist/scatter width == mat columns
#define BSHIFT 6        // 64 nodes per bucket
#define MAXNB 4096      // nb guard (scan_b / lbase capacity)
#define SMEM_BYTES 43264  // wt(34816) + xs[4][4][132](8448)

typedef __attribute__((ext_vector_type(8))) short short8;
typedef __attribute__((ext_vector_type(4))) float f32x4;

static __device__ __forceinline__ short f2bf(float f) {
    union { float f; unsigned u; } v; v.f = f;
    unsigned r = v.u + 0x7FFF + ((v.u >> 16) & 1);   // round-to-nearest-even
    return (short)(r >> 16);
}
static __device__ __forceinline__ float bf_lo(unsigned u) {
    return __builtin_bit_cast(float, u << 16);
}
static __device__ __forceinline__ float bf_hi(unsigned u) {
    return __builtin_bit_cast(float, u & 0xFFFF0000u);
}
static __device__ __forceinline__ uint4 pack8(float a0,float a1,float a2,float a3,
                                              float a4,float a5,float a6,float a7) {
    uint4 o;
    o.x = ((unsigned)(unsigned short)f2bf(a1) << 16) | (unsigned short)f2bf(a0);
    o.y = ((unsigned)(unsigned short)f2bf(a3) << 16) | (unsigned short)f2bf(a2);
    o.z = ((unsigned)(unsigned short)f2bf(a5) << 16) | (unsigned short)f2bf(a4);
    o.w = ((unsigned)(unsigned short)f2bf(a7) << 16) | (unsigned short)f2bf(a6);
    return o;
}

// ---- shared GEMM tile routine (64 rows starting at `base`) ----
static __device__ __forceinline__ void gemm_tile(
    const float* __restrict__ h, const float* __restrict__ w,
    unsigned* __restrict__ hb, int n_nodes, int base, char* smem, int tid) {
    short* wt = (short*)smem;               // [128*136] bf16 W^T  (34816 B)
    float* xs = (float*)(smem + 34816);     // [4][4][132] per-wave C bounce
    {
        int n = tid & 127;
        for (int k = tid >> 7; k < 128; k += 2)
            wt[n * 136 + k] = f2bf(w[(size_t)k * 128 + n]);
    }
    __syncthreads();

    const int wv = tid >> 6, l = tid & 63, lr = l & 15, lk = l >> 4, q = l & 15;
    if (base >= n_nodes) return;
    const int row = base + wv * 16 + lr;
    const bool valid = row < n_nodes;

    short8 af[4];
    #pragma unroll
    for (int kk = 0; kk < 4; ++kk) {
        int k0 = kk * 32 + lk * 8;
        float4 a0{0,0,0,0}, a1{0,0,0,0};
        if (valid) {
            a0 = *(const float4*)(h + (size_t)row * F + k0);
            a1 = *(const float4*)(h + (size_t)row * F + k0 + 4);
        }
        af[kk] = short8{ f2bf(a0.x), f2bf(a0.y), f2bf(a0.z), f2bf(a0.w),
                         f2bf(a1.x), f2bf(a1.y), f2bf(a1.z), f2bf(a1.w) };
    }
    f32x4 acc[8];
    #pragma unroll
    for (int n = 0; n < 8; ++n) acc[n] = f32x4{0, 0, 0, 0};
    #pragma unroll
    for (int kk = 0; kk < 4; ++kk) {
        const int kb = kk * 32 + lk * 8;
        #pragma unroll
        for (int n = 0; n < 8; ++n) {
            short8 bfr = *(const short8*)(&wt[(n * 16 + lr) * 136 + kb]);
            acc[n] = __builtin_amdgcn_mfma_f32_16x16x32_bf16(af[kk], bfr, acc[n], 0, 0, 0);
        }
    }
    // per-r bounce: row lk*4+r lives in LDS slot lk (wave-local region)
    float* xw = xs + wv * (4 * 132);
    #pragma unroll
    for (int r = 0; r < 4; ++r) {
        #pragma unroll
        for (int n = 0; n < 8; ++n)
            xw[lk * 132 + n * 16 + lr] = acc[n][r];
        int grow = base + wv * 16 + lk * 4 + r;
        float4 a = *(const float4*)&xw[lk * 132 + q * 8];
        float4 b = *(const float4*)&xw[lk * 132 + q * 8 + 4];
        uint4 o = pack8(a.x, a.y, a.z, a.w, b.x, b.y, b.z, b.w);
        if (grow < n_nodes)
            ((uint4*)hb)[(size_t)grow * 16 + q] = o;
    }
}

// ========== D1: blocks<hblk do dst-hist, rest do GEMM rows [0, ...) ========
__global__ __launch_bounds__(256) void k_gemm_hist(
    const float* __restrict__ h, const float* __restrict__ w,
    unsigned* __restrict__ hb, const int* __restrict__ dst,
    int* __restrict__ mat, int n_nodes, int n_edges, int nb, int hblk) {
    __shared__ alignas(16) char smem[SMEM_BYTES];
    const int tid = threadIdx.x;
    const int bid = blockIdx.x;

    if (bid < hblk) {
        int* lh = (int*)smem;
        for (int i = tid; i < nb; i += 256) lh[i] = 0;
        __syncthreads();
        const int epb = (n_edges + hblk - 1) / hblk;
        const int e0 = bid * epb, e1 = min(e0 + epb, n_edges);
        for (int e = e0 + tid; e < e1; e += 256)
            atomicAdd(&lh[dst[e] >> BSHIFT], 1);
        __syncthreads();
        for (int i = tid; i < nb; i += 256)
            mat[(size_t)i * NBLK + bid] = lh[i];
        return;
    }
    gemm_tile(h, w, hb, n_nodes, (bid - hblk) * 64, smem, tid);
}

// ========== D4: blocks<NBLK do binned scatter, rest do GEMM rows [row0,..) ==
__global__ __launch_bounds__(256) void k_scatter_gemm(
    const int* __restrict__ src, const int* __restrict__ dst,
    const int* __restrict__ mat, const int* __restrict__ bsum,
    unsigned* __restrict__ binned, int n_edges, int nb, int epb,
    const float* __restrict__ h, const float* __restrict__ w,
    unsigned* __restrict__ hb, int n_nodes, int row0) {
    __shared__ alignas(16) char smem[SMEM_BYTES];
    const int tid = threadIdx.x;
    const int bid = blockIdx.x;

    if (bid < NBLK) {
        int* lbase = (int*)smem;
        for (int i = tid; i < nb; i += 256) {
            int idx = i * NBLK + bid;
            lbase[i] = mat[idx] + bsum[idx >> 10];
        }
        __syncthreads();
        int e0 = bid * epb;
        int e1 = min(e0 + epb, n_edges);
        for (int e = e0 + tid; e < e1; e += 256) {
            int d = dst[e];
            int b = d >> BSHIFT;
            int pos = atomicAdd(&lbase[b], 1);   // LDS atomic only
            binned[pos] = ((unsigned)(d & ((1 << BSHIFT) - 1)) << 26) | (unsigned)src[e];
        }
        return;
    }
    gemm_tile(h, w, hb, n_nodes, row0 + (bid - NBLK) * 64, smem, tid);
}

// ========== exclusive scan (chunked; bsum holds per-chunk totals) ==========
__global__ __launch_bounds__(SCANB) void k_scan_a(const int* in, int* out,
                                                  int* bsum, int n) {
    __shared__ int tmp[SCANB];
    int i = blockIdx.x * SCANB + threadIdx.x;
    int v = (i < n) ? in[i] : 0;
    tmp[threadIdx.x] = v;
    __syncthreads();
    for (int off = 1; off < SCANB; off <<= 1) {
        int t = (threadIdx.x >= off) ? tmp[threadIdx.x - off] : 0;
        __syncthreads();
        tmp[threadIdx.x] += t;
        __syncthreads();
    }
    if (i < n) out[i] = tmp[threadIdx.x] - v;
    if (threadIdx.x == SCANB - 1) bsum[blockIdx.x] = tmp[SCANB - 1];
}

__global__ __launch_bounds__(512) void k_scan_b(int* bsum, int nb) {
    __shared__ int tmp[512];
    int i = threadIdx.x;
    int v = (i < nb) ? bsum[i] : 0;
    tmp[i] = v;
    __syncthreads();
    for (int off = 1; off < 512; off <<= 1) {
        int t = (i >= off) ? tmp[i - off] : 0;
        __syncthreads();
        tmp[i] += t;
        __syncthreads();
    }
    if (i < nb) bsum[i] = tmp[i] - v;
}

__global__ __launch_bounds__(SCANB) void k_scan_c(int* out, const int* bsum, int n) {
    int i = blockIdx.x * SCANB + threadIdx.x;
    if (i < n) out[i] += bsum[blockIdx.x];
}

// ========== per-bucket CSR finalize; scan_c folded in ======================
__global__ __launch_bounds__(256) void k_bin_to_csr(
    const unsigned* __restrict__ binned, const int* __restrict__ mat,
    const int* __restrict__ bsum, int* __restrict__ deg, int* __restrict__ offs,
    int* __restrict__ esrc, int n_edges, int n_nodes, int nb) {
    __shared__ int ldeg[64], loffs[64], lcur[64];
    int b = blockIdx.x;
    int i0 = b * NBLK;
    int start = mat[i0] + bsum[i0 >> 10];
    int end = n_edges;
    if (b + 1 < nb) {
        int i1 = (b + 1) * NBLK;
        end = mat[i1] + bsum[i1 >> 10];
    }
    int cnt = end - start;
    int base_node = b << BSHIFT;
    int nn = min(1 << BSHIFT, n_nodes - base_node);
    for (int i = threadIdx.x; i < nn; i += 256) { ldeg[i] = 0; lcur[i] = 0; }
    __syncthreads();
    for (int i = threadIdx.x; i < cnt; i += 256)
        atomicAdd(&ldeg[binned[start + i] >> 26], 1);
    __syncthreads();
    if (threadIdx.x == 0) {
        int run = 0;
        for (int i = 0; i < nn; ++i) { loffs[i] = run; run += ldeg[i]; }
    }
    __syncthreads();
    for (int i = threadIdx.x; i < nn; i += 256) {
        deg[base_node + i]  = ldeg[i];
        offs[base_node + i] = start + loffs[i];
    }
    for (int i = threadIdx.x; i < cnt; i += 256) {
        unsigned p = binned[start + i];
        int ln = p >> 26;
        int pos = start + loffs[ln] + atomicAdd(&lcur[ln], 1);  // LDS atomic
        esrc[pos] = (int)(p & ((1u << 26) - 1));
    }
}

// ========== fallback CSR build (direct, node-level scan) ===================
__global__ __launch_bounds__(256) void k_hist(const int* __restrict__ dst,
                                              int* __restrict__ deg, int n_edges) {
    int e = blockIdx.x * 256 + threadIdx.x;
    if (e < n_edges) atomicAdd(&deg[dst[e]], 1);
}

__global__ __launch_bounds__(256) void k_scatter_idx(
    const int* __restrict__ src, const int* __restrict__ dst,
    const int* __restrict__ offs, int* __restrict__ cursor,
    int* __restrict__ esrc, int n_edges) {
    int e = blockIdx.x * 256 + threadIdx.x;
    if (e >= n_edges) return;
    int d = dst[e];
    int pos = offs[d] + atomicAdd(&cursor[d], 1);
    esrc[pos] = src[e];
}

// ========== gather hW rows + norm + bias + LayerNorm + ReLU ================
// One wave per node; lane l = (g = l>>4 edge subgroup, q = l&15 chunk).
// Inner loop: 16 edges/iter, 4 independent dwordx4 loads in flight.
__global__ __launch_bounds__(256) void k_gather_ln(
    const unsigned* __restrict__ hb, const int* __restrict__ esrc,
    const int* __restrict__ offs, const int* __restrict__ deg,
    const float* __restrict__ bias, const float* __restrict__ gamma,
    const float* __restrict__ beta, float* __restrict__ out, int n_nodes) {
    int t = blockIdx.x * 256 + threadIdx.x;
    int node = t >> 6;
    int l = t & 63;
    if (node >= n_nodes) return;
    const int g = l >> 4;
    const int q = l & 15;

    const int start = offs[node];
    const int dn = deg[node];
    const int end = start + dn;

    float a0=0,a1=0,a2=0,a3=0,a4=0,a5=0,a6=0,a7=0;
    int i = start;
    for (; i + 16 <= end; i += 16) {
        int s0 = esrc[i + g];
        int s1 = esrc[i + 4 + g];
        int s2 = esrc[i + 8 + g];
        int s3 = esrc[i + 12 + g];
        uint4 v0 = *((const uint4*)(hb + (size_t)s0 * 64 + q * 4));
        uint4 v1 = *((const uint4*)(hb + (size_t)s1 * 64 + q * 4));
        uint4 v2 = *((const uint4*)(hb + (size_t)s2 * 64 + q * 4));
        uint4 v3 = *((const uint4*)(hb + (size_t)s3 * 64 + q * 4));
        a0 += (bf_lo(v0.x) + bf_lo(v1.x)) + (bf_lo(v2.x) + bf_lo(v3.x));
        a1 += (bf_hi(v0.x) + bf_hi(v1.x)) + (bf_hi(v2.x) + bf_hi(v3.x));
        a2 += (bf_lo(v0.y) + bf_lo(v1.y)) + (bf_lo(v2.y) + bf_lo(v3.y));
        a3 += (bf_hi(v0.y) + bf_hi(v1.y)) + (bf_hi(v2.y) + bf_hi(v3.y));
        a4 += (bf_lo(v0.z) + bf_lo(v1.z)) + (bf_lo(v2.z) + bf_lo(v3.z));
        a5 += (bf_hi(v0.z) + bf_hi(v1.z)) + (bf_hi(v2.z) + bf_hi(v3.z));
        a6 += (bf_lo(v0.w) + bf_lo(v1.w)) + (bf_lo(v2.w) + bf_lo(v3.w));
        a7 += (bf_hi(v0.w) + bf_hi(v1.w)) + (bf_hi(v2.w) + bf_hi(v3.w));
    }
    for (; i + 8 <= end; i += 8) {
        int s0 = esrc[i + g];
        int s1 = esrc[i + 4 + g];
        uint4 v0 = *((const uint4*)(hb + (size_t)s0 * 64 + q * 4));
        uint4 v1 = *((const uint4*)(hb + (size_t)s1 * 64 + q * 4));
        a0 += bf_lo(v0.x) + bf_lo(v1.x); a1 += bf_hi(v0.x) + bf_hi(v1.x);
        a2 += bf_lo(v0.y) + bf_lo(v1.y); a3 += bf_hi(v0.y) + bf_hi(v1.y);
        a4 += bf_lo(v0.z) + bf_lo(v1.z); a5 += bf_hi(v0.z) + bf_hi(v1.z);
        a6 += bf_lo(v0.w) + bf_lo(v1.w); a7 += bf_hi(v0.w) + bf_hi(v1.w);
    }
    for (; i < end; i += 4) {
        int e = i + g;
        if (e < end) {
            int s = esrc[e];
            uint4 v = *((const uint4*)(hb + (size_t)s * 64 + q * 4));
            a0 += bf_lo(v.x); a1 += bf_hi(v.x);
            a2 += bf_lo(v.y); a3 += bf_hi(v.y);
            a4 += bf_lo(v.z); a5 += bf_hi(v.z);
            a6 += bf_lo(v.w); a7 += bf_hi(v.w);
        }
    }
    // combine the 4 edge-subgroups
    #pragma unroll
    for (int m = 16; m <= 32; m <<= 1) {
        a0 += __shfl_xor(a0, m); a1 += __shfl_xor(a1, m);
        a2 += __shfl_xor(a2, m); a3 += __shfl_xor(a3, m);
        a4 += __shfl_xor(a4, m); a5 += __shfl_xor(a5, m);
        a6 += __shfl_xor(a6, m); a7 += __shfl_xor(a7, m);
    }
    // epilogue params loaded AFTER hot loop (keeps VGPR low in the loop)
    float4 bs0 = *(const float4*)(bias  + q * 8);
    float4 bs1 = *(const float4*)(bias  + q * 8 + 4);
    const float nv = dn > 0 ? 1.0f / (float)dn : 0.0f;
    float f0 = a0 * nv + bs0.x, f1 = a1 * nv + bs0.y;
    float f2 = a2 * nv + bs0.z, f3 = a3 * nv + bs0.w;
    float f4 = a4 * nv + bs1.x, f5 = a5 * nv + bs1.y;
    float f6 = a6 * nv + bs1.z, f7 = a7 * nv + bs1.w;

    float s  = ((f0 + f1) + (f2 + f3)) + ((f4 + f5) + (f6 + f7));
    float q2 = ((f0*f0 + f1*f1) + (f2*f2 + f3*f3)) + ((f4*f4 + f5*f5) + (f6*f6 + f7*f7));
    #pragma unroll
    for (int m = 1; m <= 8; m <<= 1) {
        s  += __shfl_xor(s, m);
        q2 += __shfl_xor(q2, m);
    }
    float mu   = s * (1.0f / F);
    float var  = q2 * (1.0f / F) - mu * mu;
    float rstd = rsqrtf(var + 1e-5f);

    if (g == 0) {
        float4 gm0 = *(const float4*)(gamma + q * 8);
        float4 gm1 = *(const float4*)(gamma + q * 8 + 4);
        float4 bt0 = *(const float4*)(beta  + q * 8);
        float4 bt1 = *(const float4*)(beta  + q * 8 + 4);
        float4 o0, o1;
        o0.x = fmaxf((f0 - mu) * rstd * gm0.x + bt0.x, 0.0f);
        o0.y = fmaxf((f1 - mu) * rstd * gm0.y + bt0.y, 0.0f);
        o0.z = fmaxf((f2 - mu) * rstd * gm0.z + bt0.z, 0.0f);
        o0.w = fmaxf((f3 - mu) * rstd * gm0.w + bt0.w, 0.0f);
        o1.x = fmaxf((f4 - mu) * rstd * gm1.x + bt1.x, 0.0f);
        o1.y = fmaxf((f5 - mu) * rstd * gm1.y + bt1.y, 0.0f);
        o1.z = fmaxf((f6 - mu) * rstd * gm1.z + bt1.z, 0.0f);
        o1.w = fmaxf((f7 - mu) * rstd * gm1.w + bt1.w, 0.0f);
        float* op = out + (size_t)node * F + q * 8;
        *(float4*)op = o0;
        *(float4*)(op + 4) = o1;
    }
}

extern "C" void kernel_launch(void* const* d_in, const int* in_sizes, int n_in,
                              void* d_out, int out_size, void* d_ws, size_t ws_size,
                              hipStream_t stream) {
    const float* h      = (const float*)d_in[0];
    const float* weight = (const float*)d_in[1];
    const float* bias   = (const float*)d_in[2];
    const float* gamma  = (const float*)d_in[3];
    const float* beta   = (const float*)d_in[4];
    const int*   src    = (const int*)d_in[5];
    const int*   dst    = (const int*)d_in[6];

    const int n_nodes = in_sizes[0] / F;
    const int n_edges = in_sizes[5];

    float* x = (float*)d_out;

    const int nb = (n_nodes + (1 << BSHIFT) - 1) >> BSHIFT;
    const int len = nb * NBLK;
    const int nscan = (len + SCANB - 1) / SCANB;
    const bool shift_ok = (nb <= MAXNB) && (nscan <= 512) && (n_nodes <= (1 << 26));

    // ws ints: deg[N] | offs[N] | esrc[E] | hb[N*64 u32] | bsum[1024] |
    //          mat[nb*NBLK] | binned[E u32]   (fallback: cursor = mat slot)
    int* deg    = (int*)d_ws;
    int* offs   = deg + n_nodes;
    int* esrc   = offs + n_nodes;
    unsigned* hb = (unsigned*)(esrc + n_edges);
    int* bsum   = (int*)(hb + (size_t)n_nodes * 64);
    int* mat    = bsum + 1024;
    unsigned* binned = (unsigned*)(mat + (size_t)len);
    int* cursor = mat;

    size_t need_common = ((size_t)2 * n_nodes + (size_t)n_edges + 1024) * sizeof(int)
                       + (size_t)n_nodes * 64 * sizeof(unsigned);
    size_t need_new  = need_common + ((size_t)len + (size_t)n_edges) * sizeof(int);
    size_t need_fall = need_common + (size_t)n_nodes * sizeof(int);
    bool use_new = shift_ok && ws_size >= need_new;

    const int gb = (n_nodes + 63) / 64;

    if (use_new) {
        // GEMM split across D1 (with hist) and D4 (with scatter)
        const int g1 = gb / 2;
        const int g2 = gb - g1;
        k_gemm_hist<<<NBLK + g1, 256, 0, stream>>>(h, weight, hb, dst, mat,
                                                   n_nodes, n_edges, nb, NBLK);
        k_scan_a<<<nscan, SCANB, 0, stream>>>(mat, mat, bsum, len);
        k_scan_b<<<1, 512, 0, stream>>>(bsum, nscan);
        const int epb = (n_edges + NBLK - 1) / NBLK;
        k_scatter_gemm<<<NBLK + g2, 256, 0, stream>>>(src, dst, mat, bsum, binned,
                                                      n_edges, nb, epb,
                                                      h, weight, hb, n_nodes, g1 * 64);
        k_bin_to_csr<<<nb, 256, 0, stream>>>(binned, mat, bsum, deg, offs, esrc,
                                             n_edges, n_nodes, nb);
        int gblocks = (int)(((size_t)n_nodes * 64 + 255) / 256);
        k_gather_ln<<<gblocks, 256, 0, stream>>>(hb, esrc, offs, deg,
                                                 bias, gamma, beta, x, n_nodes);
    } else if (ws_size >= need_fall) {
        k_gemm_hist<<<gb, 256, 0, stream>>>(h, weight, hb, dst, mat,
                                            n_nodes, n_edges, nb, 0);
        const int nscan2 = (n_nodes + SCANB - 1) / SCANB;
        hipMemsetAsync(deg, 0, (size_t)n_nodes * sizeof(int), stream);
        hipMemsetAsync(cursor, 0, (size_t)n_nodes * sizeof(int), stream);
        k_hist<<<(n_edges + 255) / 256, 256, 0, stream>>>(dst, deg, n_edges);
        k_scan_a<<<nscan2, SCANB, 0, stream>>>(deg, offs, bsum, n_nodes);
        k_scan_b<<<1, 512, 0, stream>>>(bsum, nscan2);
        k_scan_c<<<nscan2, SCANB, 0, stream>>>(offs, bsum, n_nodes);
        k_scatter_idx<<<(n_edges + 255) / 256, 256, 0, stream>>>(
            src, dst, offs, cursor, esrc, n_edges);
        int gblocks = (int)(((size_t)n_nodes * 64 + 255) / 256);
        k_gather_ln<<<gblocks, 256, 0, stream>>>(hb, esrc, offs, deg,
                                                 bias, gamma, beta, x, n_nodes);
    }
}

// Round 14
// 132.824 us; speedup vs baseline: 1.1739x; 1.0879x over previous
//
#include <hip/hip_runtime.h>

#define F 128
#define SCANB 1024
#define NBLK 256        // hist/scatter block count == mat columns
#define BSHIFT 6        // 64 nodes per bucket
#define MAXNB 2048      // nb guard (nscan <= 512 requires nb*NBLK <= 524288)
#define SMEM_BYTES 43264  // wt(34816) + xs[4][4][132](8448)

typedef __attribute__((ext_vector_type(8))) short short8;
typedef __attribute__((ext_vector_type(4))) float f32x4;

static __device__ __forceinline__ short f2bf(float f) {
    union { float f; unsigned u; } v; v.f = f;
    unsigned r = v.u + 0x7FFF + ((v.u >> 16) & 1);   // round-to-nearest-even
    return (short)(r >> 16);
}
static __device__ __forceinline__ float bf_lo(unsigned u) {
    return __builtin_bit_cast(float, u << 16);
}
static __device__ __forceinline__ float bf_hi(unsigned u) {
    return __builtin_bit_cast(float, u & 0xFFFF0000u);
}
static __device__ __forceinline__ uint4 pack8(float a0,float a1,float a2,float a3,
                                              float a4,float a5,float a6,float a7) {
    uint4 o;
    o.x = ((unsigned)(unsigned short)f2bf(a1) << 16) | (unsigned short)f2bf(a0);
    o.y = ((unsigned)(unsigned short)f2bf(a3) << 16) | (unsigned short)f2bf(a2);
    o.z = ((unsigned)(unsigned short)f2bf(a5) << 16) | (unsigned short)f2bf(a4);
    o.w = ((unsigned)(unsigned short)f2bf(a7) << 16) | (unsigned short)f2bf(a6);
    return o;
}

// ========== D1: blocks<hblk do dst-hist, rest do hW GEMM ====================
__global__ __launch_bounds__(256) void k_gemm_hist(
    const float* __restrict__ h, const float* __restrict__ w,
    unsigned* __restrict__ hb, const int* __restrict__ dst,
    int* __restrict__ mat, int n_nodes, int n_edges, int nb, int hblk) {
    __shared__ alignas(16) char smem[SMEM_BYTES];
    const int tid = threadIdx.x;
    const int bid = blockIdx.x;

    if (bid < hblk) {
        // ---- histogram role: column bid of mat ----
        int* lh = (int*)smem;
        for (int i = tid; i < nb; i += 256) lh[i] = 0;
        __syncthreads();
        const int epb = (n_edges + hblk - 1) / hblk;
        const int e0 = bid * epb, e1 = min(e0 + epb, n_edges);
        for (int e = e0 + tid; e < e1; e += 256)
            atomicAdd(&lh[dst[e] >> BSHIFT], 1);
        __syncthreads();
        for (int i = tid; i < nb; i += 256)
            mat[(size_t)i * NBLK + bid] = lh[i];
        return;
    }

    // ---- GEMM role: rows [base, base+64) ----
    short* wt = (short*)smem;               // [128*136] bf16 W^T  (34816 B)
    float* xs = (float*)(smem + 34816);     // [4][4][132] per-wave C bounce
    {
        int n = tid & 127;
        for (int k = tid >> 7; k < 128; k += 2)
            wt[n * 136 + k] = f2bf(w[(size_t)k * 128 + n]);
    }
    __syncthreads();

    const int wv = tid >> 6, l = tid & 63, lr = l & 15, lk = l >> 4, q = l & 15;
    const int base = (bid - hblk) * 64;
    if (base >= n_nodes) return;
    const int row = base + wv * 16 + lr;
    const bool valid = row < n_nodes;

    short8 af[4];
    #pragma unroll
    for (int kk = 0; kk < 4; ++kk) {
        int k0 = kk * 32 + lk * 8;
        float4 a0{0,0,0,0}, a1{0,0,0,0};
        if (valid) {
            a0 = *(const float4*)(h + (size_t)row * F + k0);
            a1 = *(const float4*)(h + (size_t)row * F + k0 + 4);
        }
        af[kk] = short8{ f2bf(a0.x), f2bf(a0.y), f2bf(a0.z), f2bf(a0.w),
                         f2bf(a1.x), f2bf(a1.y), f2bf(a1.z), f2bf(a1.w) };
    }
    f32x4 acc[8];
    #pragma unroll
    for (int n = 0; n < 8; ++n) acc[n] = f32x4{0, 0, 0, 0};
    #pragma unroll
    for (int kk = 0; kk < 4; ++kk) {
        const int kb = kk * 32 + lk * 8;
        #pragma unroll
        for (int n = 0; n < 8; ++n) {
            short8 bfr = *(const short8*)(&wt[(n * 16 + lr) * 136 + kb]);
            acc[n] = __builtin_amdgcn_mfma_f32_16x16x32_bf16(af[kk], bfr, acc[n], 0, 0, 0);
        }
    }
    // per-r bounce: row lk*4+r lives in LDS slot lk (wave-local region)
    float* xw = xs + wv * (4 * 132);
    #pragma unroll
    for (int r = 0; r < 4; ++r) {
        #pragma unroll
        for (int n = 0; n < 8; ++n)
            xw[lk * 132 + n * 16 + lr] = acc[n][r];
        int grow = base + wv * 16 + lk * 4 + r;
        float4 a = *(const float4*)&xw[lk * 132 + q * 8];
        float4 b = *(const float4*)&xw[lk * 132 + q * 8 + 4];
        uint4 o = pack8(a.x, a.y, a.z, a.w, b.x, b.y, b.z, b.w);
        if (grow < n_nodes)
            ((uint4*)hb)[(size_t)grow * 16 + q] = o;
    }
}

// ========== exclusive scan (chunked; bsum holds per-chunk totals) ==========
__global__ __launch_bounds__(SCANB) void k_scan_a(const int* in, int* out,
                                                  int* bsum, int n) {
    __shared__ int tmp[SCANB];
    int i = blockIdx.x * SCANB + threadIdx.x;
    int v = (i < n) ? in[i] : 0;
    tmp[threadIdx.x] = v;
    __syncthreads();
    for (int off = 1; off < SCANB; off <<= 1) {
        int t = (threadIdx.x >= off) ? tmp[threadIdx.x - off] : 0;
        __syncthreads();
        tmp[threadIdx.x] += t;
        __syncthreads();
    }
    if (i < n) out[i] = tmp[threadIdx.x] - v;
    if (threadIdx.x == SCANB - 1) bsum[blockIdx.x] = tmp[SCANB - 1];
}

__global__ __launch_bounds__(512) void k_scan_b(int* bsum, int nb) {
    __shared__ int tmp[512];
    int i = threadIdx.x;
    int v = (i < nb) ? bsum[i] : 0;
    tmp[i] = v;
    __syncthreads();
    for (int off = 1; off < 512; off <<= 1) {
        int t = (i >= off) ? tmp[i - off] : 0;
        __syncthreads();
        tmp[i] += t;
        __syncthreads();
    }
    if (i < nb) bsum[i] = tmp[i] - v;
}

__global__ __launch_bounds__(SCANB) void k_scan_c(int* out, const int* bsum, int n) {
    int i = blockIdx.x * SCANB + threadIdx.x;
    if (i < n) out[i] += bsum[blockIdx.x];
}

// ========== binned scatter (512 thr, all CUs); scan_c folded via bsum ======
__global__ __launch_bounds__(512) void k_part_scatter(
    const int* __restrict__ src, const int* __restrict__ dst,
    const int* __restrict__ mat, const int* __restrict__ bsum,
    unsigned* __restrict__ binned, int n_edges, int nb, int epb) {
    __shared__ int lbase[MAXNB];
    const int bid = blockIdx.x;
    for (int i = threadIdx.x; i < nb; i += 512) {
        int idx = i * NBLK + bid;
        lbase[i] = mat[idx] + bsum[idx >> 10];
    }
    __syncthreads();
    int e0 = bid * epb;
    int e1 = min(e0 + epb, n_edges);
    for (int e = e0 + threadIdx.x; e < e1; e += 512) {
        int d = dst[e];
        int b = d >> BSHIFT;
        int pos = atomicAdd(&lbase[b], 1);   // LDS atomic only
        binned[pos] = ((unsigned)(d & ((1 << BSHIFT) - 1)) << 26) | (unsigned)src[e];
    }
}

// ========== per-bucket CSR finalize; scan_c folded in ======================
__global__ __launch_bounds__(256) void k_bin_to_csr(
    const unsigned* __restrict__ binned, const int* __restrict__ mat,
    const int* __restrict__ bsum, int* __restrict__ deg, int* __restrict__ offs,
    int* __restrict__ esrc, int n_edges, int n_nodes, int nb) {
    __shared__ int ldeg[64], loffs[64], lcur[64];
    int b = blockIdx.x;
    int i0 = b * NBLK;
    int start = mat[i0] + bsum[i0 >> 10];
    int end = n_edges;
    if (b + 1 < nb) {
        int i1 = (b + 1) * NBLK;
        end = mat[i1] + bsum[i1 >> 10];
    }
    int cnt = end - start;
    int base_node = b << BSHIFT;
    int nn = min(1 << BSHIFT, n_nodes - base_node);
    for (int i = threadIdx.x; i < nn; i += 256) { ldeg[i] = 0; lcur[i] = 0; }
    __syncthreads();
    for (int i = threadIdx.x; i < cnt; i += 256)
        atomicAdd(&ldeg[binned[start + i] >> 26], 1);
    __syncthreads();
    if (threadIdx.x == 0) {
        int run = 0;
        for (int i = 0; i < nn; ++i) { loffs[i] = run; run += ldeg[i]; }
    }
    __syncthreads();
    for (int i = threadIdx.x; i < nn; i += 256) {
        deg[base_node + i]  = ldeg[i];
        offs[base_node + i] = start + loffs[i];
    }
    for (int i = threadIdx.x; i < cnt; i += 256) {
        unsigned p = binned[start + i];
        int ln = p >> 26;
        int pos = start + loffs[ln] + atomicAdd(&lcur[ln], 1);  // LDS atomic
        esrc[pos] = (int)(p & ((1u << 26) - 1));
    }
}

// ========== fallback CSR build (direct, node-level scan) ===================
__global__ __launch_bounds__(256) void k_hist(const int* __restrict__ dst,
                                              int* __restrict__ deg, int n_edges) {
    int e = blockIdx.x * 256 + threadIdx.x;
    if (e < n_edges) atomicAdd(&deg[dst[e]], 1);
}

__global__ __launch_bounds__(256) void k_scatter_idx(
    const int* __restrict__ src, const int* __restrict__ dst,
    const int* __restrict__ offs, int* __restrict__ cursor,
    int* __restrict__ esrc, int n_edges) {
    int e = blockIdx.x * 256 + threadIdx.x;
    if (e >= n_edges) return;
    int d = dst[e];
    int pos = offs[d] + atomicAdd(&cursor[d], 1);
    esrc[pos] = src[e];
}

// ========== gather hW rows + norm + bias + LayerNorm + ReLU ================
// One wave per node; lane l = (g = l>>4 edge subgroup, q = l&15 chunk).
__global__ __launch_bounds__(256) void k_gather_ln(
    const unsigned* __restrict__ hb, const int* __restrict__ esrc,
    const int* __restrict__ offs, const int* __restrict__ deg,
    const float* __restrict__ bias, const float* __restrict__ gamma,
    const float* __restrict__ beta, float* __restrict__ out, int n_nodes) {
    int t = blockIdx.x * 256 + threadIdx.x;
    int node = t >> 6;
    int l = t & 63;
    if (node >= n_nodes) return;
    const int g = l >> 4;
    const int q = l & 15;

    const int start = offs[node];
    const int dn = deg[node];
    const int end = start + dn;

    float a0=0,a1=0,a2=0,a3=0,a4=0,a5=0,a6=0,a7=0;
    int i = start;
    for (; i + 16 <= end; i += 16) {
        int s0 = esrc[i + g];
        int s1 = esrc[i + 4 + g];
        int s2 = esrc[i + 8 + g];
        int s3 = esrc[i + 12 + g];
        uint4 v0 = *((const uint4*)(hb + (size_t)s0 * 64 + q * 4));
        uint4 v1 = *((const uint4*)(hb + (size_t)s1 * 64 + q * 4));
        uint4 v2 = *((const uint4*)(hb + (size_t)s2 * 64 + q * 4));
        uint4 v3 = *((const uint4*)(hb + (size_t)s3 * 64 + q * 4));
        a0 += (bf_lo(v0.x) + bf_lo(v1.x)) + (bf_lo(v2.x) + bf_lo(v3.x));
        a1 += (bf_hi(v0.x) + bf_hi(v1.x)) + (bf_hi(v2.x) + bf_hi(v3.x));
        a2 += (bf_lo(v0.y) + bf_lo(v1.y)) + (bf_lo(v2.y) + bf_lo(v3.y));
        a3 += (bf_hi(v0.y) + bf_hi(v1.y)) + (bf_hi(v2.y) + bf_hi(v3.y));
        a4 += (bf_lo(v0.z) + bf_lo(v1.z)) + (bf_lo(v2.z) + bf_lo(v3.z));
        a5 += (bf_hi(v0.z) + bf_hi(v1.z)) + (bf_hi(v2.z) + bf_hi(v3.z));
        a6 += (bf_lo(v0.w) + bf_lo(v1.w)) + (bf_lo(v2.w) + bf_lo(v3.w));
        a7 += (bf_hi(v0.w) + bf_hi(v1.w)) + (bf_hi(v2.w) + bf_hi(v3.w));
    }
    for (; i + 8 <= end; i += 8) {
        int s0 = esrc[i + g];
        int s1 = esrc[i + 4 + g];
        uint4 v0 = *((const uint4*)(hb + (size_t)s0 * 64 + q * 4));
        uint4 v1 = *((const uint4*)(hb + (size_t)s1 * 64 + q * 4));
        a0 += bf_lo(v0.x) + bf_lo(v1.x); a1 += bf_hi(v0.x) + bf_hi(v1.x);
        a2 += bf_lo(v0.y) + bf_lo(v1.y); a3 += bf_hi(v0.y) + bf_hi(v1.y);
        a4 += bf_lo(v0.z) + bf_lo(v1.z); a5 += bf_hi(v0.z) + bf_hi(v1.z);
        a6 += bf_lo(v0.w) + bf_lo(v1.w); a7 += bf_hi(v0.w) + bf_hi(v1.w);
    }
    for (; i < end; i += 4) {
        int e = i + g;
        if (e < end) {
            int s = esrc[e];
            uint4 v = *((const uint4*)(hb + (size_t)s * 64 + q * 4));
            a0 += bf_lo(v.x); a1 += bf_hi(v.x);
            a2 += bf_lo(v.y); a3 += bf_hi(v.y);
            a4 += bf_lo(v.z); a5 += bf_hi(v.z);
            a6 += bf_lo(v.w); a7 += bf_hi(v.w);
        }
    }
    #pragma unroll
    for (int m = 16; m <= 32; m <<= 1) {
        a0 += __shfl_xor(a0, m); a1 += __shfl_xor(a1, m);
        a2 += __shfl_xor(a2, m); a3 += __shfl_xor(a3, m);
        a4 += __shfl_xor(a4, m); a5 += __shfl_xor(a5, m);
        a6 += __shfl_xor(a6, m); a7 += __shfl_xor(a7, m);
    }
    float4 bs0 = *(const float4*)(bias  + q * 8);
    float4 bs1 = *(const float4*)(bias  + q * 8 + 4);
    const float nv = dn > 0 ? 1.0f / (float)dn : 0.0f;
    float f0 = a0 * nv + bs0.x, f1 = a1 * nv + bs0.y;
    float f2 = a2 * nv + bs0.z, f3 = a3 * nv + bs0.w;
    float f4 = a4 * nv + bs1.x, f5 = a5 * nv + bs1.y;
    float f6 = a6 * nv + bs1.z, f7 = a7 * nv + bs1.w;

    float s  = ((f0 + f1) + (f2 + f3)) + ((f4 + f5) + (f6 + f7));
    float q2 = ((f0*f0 + f1*f1) + (f2*f2 + f3*f3)) + ((f4*f4 + f5*f5) + (f6*f6 + f7*f7));
    #pragma unroll
    for (int m = 1; m <= 8; m <<= 1) {
        s  += __shfl_xor(s, m);
        q2 += __shfl_xor(q2, m);
    }
    float mu   = s * (1.0f / F);
    float var  = q2 * (1.0f / F) - mu * mu;
    float rstd = rsqrtf(var + 1e-5f);

    if (g == 0) {
        float4 gm0 = *(const float4*)(gamma + q * 8);
        float4 gm1 = *(const float4*)(gamma + q * 8 + 4);
        float4 bt0 = *(const float4*)(beta  + q * 8);
        float4 bt1 = *(const float4*)(beta  + q * 8 + 4);
        float4 o0, o1;
        o0.x = fmaxf((f0 - mu) * rstd * gm0.x + bt0.x, 0.0f);
        o0.y = fmaxf((f1 - mu) * rstd * gm0.y + bt0.y, 0.0f);
        o0.z = fmaxf((f2 - mu) * rstd * gm0.z + bt0.z, 0.0f);
        o0.w = fmaxf((f3 - mu) * rstd * gm0.w + bt0.w, 0.0f);
        o1.x = fmaxf((f4 - mu) * rstd * gm1.x + bt1.x, 0.0f);
        o1.y = fmaxf((f5 - mu) * rstd * gm1.y + bt1.y, 0.0f);
        o1.z = fmaxf((f6 - mu) * rstd * gm1.z + bt1.z, 0.0f);
        o1.w = fmaxf((f7 - mu) * rstd * gm1.w + bt1.w, 0.0f);
        float* op = out + (size_t)node * F + q * 8;
        *(float4*)op = o0;
        *(float4*)(op + 4) = o1;
    }
}

extern "C" void kernel_launch(void* const* d_in, const int* in_sizes, int n_in,
                              void* d_out, int out_size, void* d_ws, size_t ws_size,
                              hipStream_t stream) {
    const float* h      = (const float*)d_in[0];
    const float* weight = (const float*)d_in[1];
    const float* bias   = (const float*)d_in[2];
    const float* gamma  = (const float*)d_in[3];
    const float* beta   = (const float*)d_in[4];
    const int*   src    = (const int*)d_in[5];
    const int*   dst    = (const int*)d_in[6];

    const int n_nodes = in_sizes[0] / F;
    const int n_edges = in_sizes[5];

    float* x = (float*)d_out;

    const int nb = (n_nodes + (1 << BSHIFT) - 1) >> BSHIFT;
    const int len = nb * NBLK;
    const int nscan = (len + SCANB - 1) / SCANB;
    const bool shift_ok = (nb <= MAXNB) && (nscan <= 512) && (n_nodes <= (1 << 26));

    // ws ints: deg[N] | offs[N] | esrc[E] | hb[N*64 u32] | bsum[1024] |
    //          mat[nb*NBLK] | binned[E u32]   (fallback: cursor = mat slot)
    int* deg    = (int*)d_ws;
    int* offs   = deg + n_nodes;
    int* esrc   = offs + n_nodes;
    unsigned* hb = (unsigned*)(esrc + n_edges);
    int* bsum   = (int*)(hb + (size_t)n_nodes * 64);
    int* mat    = bsum + 1024;
    unsigned* binned = (unsigned*)(mat + (size_t)len);
    int* cursor = mat;

    size_t need_common = ((size_t)2 * n_nodes + (size_t)n_edges + 1024) * sizeof(int)
                       + (size_t)n_nodes * 64 * sizeof(unsigned);
    size_t need_new  = need_common + ((size_t)len + (size_t)n_edges) * sizeof(int);
    size_t need_fall = need_common + (size_t)n_nodes * sizeof(int);
    bool use_new = shift_ok && ws_size >= need_new;

    const int gb = (n_nodes + 63) / 64;

    if (use_new) {
        k_gemm_hist<<<NBLK + gb, 256, 0, stream>>>(h, weight, hb, dst, mat,
                                                   n_nodes, n_edges, nb, NBLK);
        k_scan_a<<<nscan, SCANB, 0, stream>>>(mat, mat, bsum, len);
        k_scan_b<<<1, 512, 0, stream>>>(bsum, nscan);
        const int epb = (n_edges + NBLK - 1) / NBLK;
        k_part_scatter<<<NBLK, 512, 0, stream>>>(src, dst, mat, bsum, binned,
                                                 n_edges, nb, epb);
        k_bin_to_csr<<<nb, 256, 0, stream>>>(binned, mat, bsum, deg, offs, esrc,
                                             n_edges, n_nodes, nb);
        int gblocks = (int)(((size_t)n_nodes * 64 + 255) / 256);
        k_gather_ln<<<gblocks, 256, 0, stream>>>(hb, esrc, offs, deg,
                                                 bias, gamma, beta, x, n_nodes);
    } else if (ws_size >= need_fall) {
        k_gemm_hist<<<gb, 256, 0, stream>>>(h, weight, hb, dst, mat,
                                            n_nodes, n_edges, nb, 0);
        const int nscan2 = (n_nodes + SCANB - 1) / SCANB;
        hipMemsetAsync(deg, 0, (size_t)n_nodes * sizeof(int), stream);
        hipMemsetAsync(cursor, 0, (size_t)n_nodes * sizeof(int), stream);
        k_hist<<<(n_edges + 255) / 256, 256, 0, stream>>>(dst, deg, n_edges);
        k_scan_a<<<nscan2, SCANB, 0, stream>>>(deg, offs, bsum, n_nodes);
        k_scan_b<<<1, 512, 0, stream>>>(bsum, nscan2);
        k_scan_c<<<nscan2, SCANB, 0, stream>>>(offs, bsum, n_nodes);
        k_scatter_idx<<<(n_edges + 255) / 256, 256, 0, stream>>>(
            src, dst, offs, cursor, esrc, n_edges);
        int gblocks = (int)(((size_t)n_nodes * 64 + 255) / 256);
        k_gather_ln<<<gblocks, 256, 0, stream>>>(hb, esrc, offs, deg,
                                                 bias, gamma, beta, x, n_nodes);
    }
}

// Round 15
// 129.559 us; speedup vs baseline: 1.2035x; 1.0252x over previous
//
#include <hip/hip_runtime.h>
#include <hip/hip_fp16.h>

#define F 128
#define SCANB 1024
#define NBLK 256        // hist/scatter block count == mat columns
#define BSHIFT 7        // 128 nodes per bucket
#define MAXNB 2048      // nb guard (lbase capacity; nscan<=512)
#define SMEM_BYTES 43264  // wt(34816) + xs[4][4][132](8448)

typedef __attribute__((ext_vector_type(8))) short short8;
typedef __attribute__((ext_vector_type(4))) float f32x4;

static __device__ __forceinline__ short f2bf(float f) {
    union { float f; unsigned u; } v; v.f = f;
    unsigned r = v.u + 0x7FFF + ((v.u >> 16) & 1);   // round-to-nearest-even
    return (short)(r >> 16);
}
static __device__ __forceinline__ __half2 h2(unsigned u) {
    return __builtin_bit_cast(__half2, u);
}
// pack 8 f32 -> 4x f16-pairs
static __device__ __forceinline__ uint4 pack8h(float a0,float a1,float a2,float a3,
                                               float a4,float a5,float a6,float a7) {
    uint4 o;
    o.x = __builtin_bit_cast(unsigned, __floats2half2_rn(a0, a1));
    o.y = __builtin_bit_cast(unsigned, __floats2half2_rn(a2, a3));
    o.z = __builtin_bit_cast(unsigned, __floats2half2_rn(a4, a5));
    o.w = __builtin_bit_cast(unsigned, __floats2half2_rn(a6, a7));
    return o;
}

// ========== D1: blocks<hblk do dst-hist, rest do hW GEMM (f16 out) =========
__global__ __launch_bounds__(256) void k_gemm_hist(
    const float* __restrict__ h, const float* __restrict__ w,
    unsigned* __restrict__ hb, const int* __restrict__ dst,
    int* __restrict__ mat, int n_nodes, int n_edges, int nb, int hblk) {
    __shared__ alignas(16) char smem[SMEM_BYTES];
    const int tid = threadIdx.x;
    const int bid = blockIdx.x;

    if (bid < hblk) {
        // ---- histogram role: column bid of mat ----
        int* lh = (int*)smem;
        for (int i = tid; i < nb; i += 256) lh[i] = 0;
        __syncthreads();
        const int epb = (n_edges + hblk - 1) / hblk;
        const int e0 = bid * epb, e1 = min(e0 + epb, n_edges);
        for (int e = e0 + tid; e < e1; e += 256)
            atomicAdd(&lh[dst[e] >> BSHIFT], 1);
        __syncthreads();
        for (int i = tid; i < nb; i += 256)
            mat[(size_t)i * NBLK + bid] = lh[i];
        return;
    }

    // ---- GEMM role: rows [base, base+64) ----
    short* wt = (short*)smem;               // [128*136] bf16 W^T  (34816 B)
    float* xs = (float*)(smem + 34816);     // [4][4][132] per-wave C bounce
    {
        int n = tid & 127;
        for (int k = tid >> 7; k < 128; k += 2)
            wt[n * 136 + k] = f2bf(w[(size_t)k * 128 + n]);
    }
    __syncthreads();

    const int wv = tid >> 6, l = tid & 63, lr = l & 15, lk = l >> 4, q = l & 15;
    const int base = (bid - hblk) * 64;
    if (base >= n_nodes) return;
    const int row = base + wv * 16 + lr;
    const bool valid = row < n_nodes;

    short8 af[4];
    #pragma unroll
    for (int kk = 0; kk < 4; ++kk) {
        int k0 = kk * 32 + lk * 8;
        float4 a0{0,0,0,0}, a1{0,0,0,0};
        if (valid) {
            a0 = *(const float4*)(h + (size_t)row * F + k0);
            a1 = *(const float4*)(h + (size_t)row * F + k0 + 4);
        }
        af[kk] = short8{ f2bf(a0.x), f2bf(a0.y), f2bf(a0.z), f2bf(a0.w),
                         f2bf(a1.x), f2bf(a1.y), f2bf(a1.z), f2bf(a1.w) };
    }
    f32x4 acc[8];
    #pragma unroll
    for (int n = 0; n < 8; ++n) acc[n] = f32x4{0, 0, 0, 0};
    #pragma unroll
    for (int kk = 0; kk < 4; ++kk) {
        const int kb = kk * 32 + lk * 8;
        #pragma unroll
        for (int n = 0; n < 8; ++n) {
            short8 bfr = *(const short8*)(&wt[(n * 16 + lr) * 136 + kb]);
            acc[n] = __builtin_amdgcn_mfma_f32_16x16x32_bf16(af[kk], bfr, acc[n], 0, 0, 0);
        }
    }
    // per-r bounce: row lk*4+r lives in LDS slot lk (wave-local region)
    float* xw = xs + wv * (4 * 132);
    #pragma unroll
    for (int r = 0; r < 4; ++r) {
        #pragma unroll
        for (int n = 0; n < 8; ++n)
            xw[lk * 132 + n * 16 + lr] = acc[n][r];
        int grow = base + wv * 16 + lk * 4 + r;
        float4 a = *(const float4*)&xw[lk * 132 + q * 8];
        float4 b = *(const float4*)&xw[lk * 132 + q * 8 + 4];
        uint4 o = pack8h(a.x, a.y, a.z, a.w, b.x, b.y, b.z, b.w);
        if (grow < n_nodes)
            ((uint4*)hb)[(size_t)grow * 16 + q] = o;
    }
}

// ========== exclusive scan (chunked; bsum holds per-chunk totals) ==========
__global__ __launch_bounds__(SCANB) void k_scan_a(const int* in, int* out,
                                                  int* bsum, int n) {
    __shared__ int tmp[SCANB];
    int i = blockIdx.x * SCANB + threadIdx.x;
    int v = (i < n) ? in[i] : 0;
    tmp[threadIdx.x] = v;
    __syncthreads();
    for (int off = 1; off < SCANB; off <<= 1) {
        int t = (threadIdx.x >= off) ? tmp[threadIdx.x - off] : 0;
        __syncthreads();
        tmp[threadIdx.x] += t;
        __syncthreads();
    }
    if (i < n) out[i] = tmp[threadIdx.x] - v;
    if (threadIdx.x == SCANB - 1) bsum[blockIdx.x] = tmp[SCANB - 1];
}

__global__ __launch_bounds__(512) void k_scan_b(int* bsum, int nb) {
    __shared__ int tmp[512];
    int i = threadIdx.x;
    int v = (i < nb) ? bsum[i] : 0;
    tmp[i] = v;
    __syncthreads();
    for (int off = 1; off < 512; off <<= 1) {
        int t = (i >= off) ? tmp[i - off] : 0;
        __syncthreads();
        tmp[i] += t;
        __syncthreads();
    }
    if (i < nb) bsum[i] = tmp[i] - v;
}

__global__ __launch_bounds__(SCANB) void k_scan_c(int* out, const int* bsum, int n) {
    int i = blockIdx.x * SCANB + threadIdx.x;
    if (i < n) out[i] += bsum[blockIdx.x];
}

// ========== binned scatter (512 thr, all CUs); scan_c folded via bsum ======
__global__ __launch_bounds__(512) void k_part_scatter(
    const int* __restrict__ src, const int* __restrict__ dst,
    const int* __restrict__ mat, const int* __restrict__ bsum,
    unsigned* __restrict__ binned, int n_edges, int nb, int epb) {
    __shared__ int lbase[MAXNB];
    const int bid = blockIdx.x;
    for (int i = threadIdx.x; i < nb; i += 512) {
        int idx = i * NBLK + bid;
        lbase[i] = mat[idx] + bsum[idx >> 10];
    }
    __syncthreads();
    int e0 = bid * epb;
    int e1 = min(e0 + epb, n_edges);
    for (int e = e0 + threadIdx.x; e < e1; e += 512) {
        int d = dst[e];
        int b = d >> BSHIFT;
        int pos = atomicAdd(&lbase[b], 1);   // LDS atomic only
        binned[pos] = ((unsigned)(d & ((1 << BSHIFT) - 1)) << 25) | (unsigned)src[e];
    }
}

// ========== per-bucket CSR finalize; scan_c folded in ======================
__global__ __launch_bounds__(256) void k_bin_to_csr(
    const unsigned* __restrict__ binned, const int* __restrict__ mat,
    const int* __restrict__ bsum, int* __restrict__ deg, int* __restrict__ offs,
    int* __restrict__ esrc, int n_edges, int n_nodes, int nb) {
    __shared__ int ldeg[128], loffs[128], lcur[128];
    int b = blockIdx.x;
    int i0 = b * NBLK;
    int start = mat[i0] + bsum[i0 >> 10];
    int end = n_edges;
    if (b + 1 < nb) {
        int i1 = (b + 1) * NBLK;
        end = mat[i1] + bsum[i1 >> 10];
    }
    int cnt = end - start;
    int base_node = b << BSHIFT;
    int nn = min(1 << BSHIFT, n_nodes - base_node);
    for (int i = threadIdx.x; i < nn; i += 256) { ldeg[i] = 0; lcur[i] = 0; }
    __syncthreads();
    for (int i = threadIdx.x; i < cnt; i += 256)
        atomicAdd(&ldeg[binned[start + i] >> 25], 1);
    __syncthreads();
    if (threadIdx.x == 0) {
        int run = 0;
        for (int i = 0; i < nn; ++i) { loffs[i] = run; run += ldeg[i]; }
    }
    __syncthreads();
    for (int i = threadIdx.x; i < nn; i += 256) {
        deg[base_node + i]  = ldeg[i];
        offs[base_node + i] = start + loffs[i];
    }
    for (int i = threadIdx.x; i < cnt; i += 256) {
        unsigned p = binned[start + i];
        int ln = p >> 25;
        int pos = start + loffs[ln] + atomicAdd(&lcur[ln], 1);  // LDS atomic
        esrc[pos] = (int)(p & ((1u << 25) - 1));
    }
}

// ========== fallback CSR build (direct, node-level scan) ===================
__global__ __launch_bounds__(256) void k_hist(const int* __restrict__ dst,
                                              int* __restrict__ deg, int n_edges) {
    int e = blockIdx.x * 256 + threadIdx.x;
    if (e < n_edges) atomicAdd(&deg[dst[e]], 1);
}

__global__ __launch_bounds__(256) void k_scatter_idx(
    const int* __restrict__ src, const int* __restrict__ dst,
    const int* __restrict__ offs, int* __restrict__ cursor,
    int* __restrict__ esrc, int n_edges) {
    int e = blockIdx.x * 256 + threadIdx.x;
    if (e >= n_edges) return;
    int d = dst[e];
    int pos = offs[d] + atomicAdd(&cursor[d], 1);
    esrc[pos] = src[e];
}

// ========== gather hW rows (f16) + norm + bias + LayerNorm + ReLU ==========
// One wave per node; lane l = (g = l>>4 edge subgroup, q = l&15 chunk).
// Accumulate in packed f16 (v_pk_add_f16): 4 VALU per uint4 instead of 16.
__global__ __launch_bounds__(256) void k_gather_ln(
    const unsigned* __restrict__ hb, const int* __restrict__ esrc,
    const int* __restrict__ offs, const int* __restrict__ deg,
    const float* __restrict__ bias, const float* __restrict__ gamma,
    const float* __restrict__ beta, float* __restrict__ out, int n_nodes) {
    int t = blockIdx.x * 256 + threadIdx.x;
    int node = t >> 6;
    int l = t & 63;
    if (node >= n_nodes) return;
    const int g = l >> 4;
    const int q = l & 15;

    const int start = offs[node];
    const int dn = deg[node];
    const int end = start + dn;

    __half2 c0 = __floats2half2_rn(0.f, 0.f);
    __half2 c1 = c0, c2 = c0, c3 = c0;
    int i = start;
    for (; i + 16 <= end; i += 16) {
        int s0 = esrc[i + g];
        int s1 = esrc[i + 4 + g];
        int s2 = esrc[i + 8 + g];
        int s3 = esrc[i + 12 + g];
        uint4 v0 = *((const uint4*)(hb + (size_t)s0 * 64 + q * 4));
        uint4 v1 = *((const uint4*)(hb + (size_t)s1 * 64 + q * 4));
        uint4 v2 = *((const uint4*)(hb + (size_t)s2 * 64 + q * 4));
        uint4 v3 = *((const uint4*)(hb + (size_t)s3 * 64 + q * 4));
        c0 = __hadd2(c0, __hadd2(__hadd2(h2(v0.x), h2(v1.x)), __hadd2(h2(v2.x), h2(v3.x))));
        c1 = __hadd2(c1, __hadd2(__hadd2(h2(v0.y), h2(v1.y)), __hadd2(h2(v2.y), h2(v3.y))));
        c2 = __hadd2(c2, __hadd2(__hadd2(h2(v0.z), h2(v1.z)), __hadd2(h2(v2.z), h2(v3.z))));
        c3 = __hadd2(c3, __hadd2(__hadd2(h2(v0.w), h2(v1.w)), __hadd2(h2(v2.w), h2(v3.w))));
    }
    for (; i + 8 <= end; i += 8) {
        int s0 = esrc[i + g];
        int s1 = esrc[i + 4 + g];
        uint4 v0 = *((const uint4*)(hb + (size_t)s0 * 64 + q * 4));
        uint4 v1 = *((const uint4*)(hb + (size_t)s1 * 64 + q * 4));
        c0 = __hadd2(c0, __hadd2(h2(v0.x), h2(v1.x)));
        c1 = __hadd2(c1, __hadd2(h2(v0.y), h2(v1.y)));
        c2 = __hadd2(c2, __hadd2(h2(v0.z), h2(v1.z)));
        c3 = __hadd2(c3, __hadd2(h2(v0.w), h2(v1.w)));
    }
    for (; i < end; i += 4) {
        int e = i + g;
        if (e < end) {
            int s = esrc[e];
            uint4 v = *((const uint4*)(hb + (size_t)s * 64 + q * 4));
            c0 = __hadd2(c0, h2(v.x));
            c1 = __hadd2(c1, h2(v.y));
            c2 = __hadd2(c2, h2(v.z));
            c3 = __hadd2(c3, h2(v.w));
        }
    }
    // unpack to f32 once
    float2 p0 = __half22float2(c0), p1 = __half22float2(c1);
    float2 p2 = __half22float2(c2), p3 = __half22float2(c3);
    float a0 = p0.x, a1 = p0.y, a2 = p1.x, a3 = p1.y;
    float a4 = p2.x, a5 = p2.y, a6 = p3.x, a7 = p3.y;

    // combine the 4 edge-subgroups
    #pragma unroll
    for (int m = 16; m <= 32; m <<= 1) {
        a0 += __shfl_xor(a0, m); a1 += __shfl_xor(a1, m);
        a2 += __shfl_xor(a2, m); a3 += __shfl_xor(a3, m);
        a4 += __shfl_xor(a4, m); a5 += __shfl_xor(a5, m);
        a6 += __shfl_xor(a6, m); a7 += __shfl_xor(a7, m);
    }
    float4 bs0 = *(const float4*)(bias  + q * 8);
    float4 bs1 = *(const float4*)(bias  + q * 8 + 4);
    const float nv = dn > 0 ? 1.0f / (float)dn : 0.0f;
    float f0 = a0 * nv + bs0.x, f1 = a1 * nv + bs0.y;
    float f2 = a2 * nv + bs0.z, f3 = a3 * nv + bs0.w;
    float f4 = a4 * nv + bs1.x, f5 = a5 * nv + bs1.y;
    float f6 = a6 * nv + bs1.z, f7 = a7 * nv + bs1.w;

    float s  = ((f0 + f1) + (f2 + f3)) + ((f4 + f5) + (f6 + f7));
    float q2 = ((f0*f0 + f1*f1) + (f2*f2 + f3*f3)) + ((f4*f4 + f5*f5) + (f6*f6 + f7*f7));
    #pragma unroll
    for (int m = 1; m <= 8; m <<= 1) {
        s  += __shfl_xor(s, m);
        q2 += __shfl_xor(q2, m);
    }
    float mu   = s * (1.0f / F);
    float var  = q2 * (1.0f / F) - mu * mu;
    float rstd = rsqrtf(var + 1e-5f);

    if (g == 0) {
        float4 gm0 = *(const float4*)(gamma + q * 8);
        float4 gm1 = *(const float4*)(gamma + q * 8 + 4);
        float4 bt0 = *(const float4*)(beta  + q * 8);
        float4 bt1 = *(const float4*)(beta  + q * 8 + 4);
        float4 o0, o1;
        o0.x = fmaxf((f0 - mu) * rstd * gm0.x + bt0.x, 0.0f);
        o0.y = fmaxf((f1 - mu) * rstd * gm0.y + bt0.y, 0.0f);
        o0.z = fmaxf((f2 - mu) * rstd * gm0.z + bt0.z, 0.0f);
        o0.w = fmaxf((f3 - mu) * rstd * gm0.w + bt0.w, 0.0f);
        o1.x = fmaxf((f4 - mu) * rstd * gm1.x + bt1.x, 0.0f);
        o1.y = fmaxf((f5 - mu) * rstd * gm1.y + bt1.y, 0.0f);
        o1.z = fmaxf((f6 - mu) * rstd * gm1.z + bt1.z, 0.0f);
        o1.w = fmaxf((f7 - mu) * rstd * gm1.w + bt1.w, 0.0f);
        float* op = out + (size_t)node * F + q * 8;
        *(float4*)op = o0;
        *(float4*)(op + 4) = o1;
    }
}

extern "C" void kernel_launch(void* const* d_in, const int* in_sizes, int n_in,
                              void* d_out, int out_size, void* d_ws, size_t ws_size,
                              hipStream_t stream) {
    const float* h      = (const float*)d_in[0];
    const float* weight = (const float*)d_in[1];
    const float* bias   = (const float*)d_in[2];
    const float* gamma  = (const float*)d_in[3];
    const float* beta   = (const float*)d_in[4];
    const int*   src    = (const int*)d_in[5];
    const int*   dst    = (const int*)d_in[6];

    const int n_nodes = in_sizes[0] / F;
    const int n_edges = in_sizes[5];

    float* x = (float*)d_out;

    const int nb = (n_nodes + (1 << BSHIFT) - 1) >> BSHIFT;
    const int len = nb * NBLK;
    const int nscan = (len + SCANB - 1) / SCANB;
    // guards: lbase/scan capacity; pack = 7-bit local dst + 25-bit src
    const bool shift_ok = (nb <= MAXNB) && (nscan <= 512) && (n_nodes <= (1 << 25));

    // ws ints: deg[N] | offs[N] | esrc[E] | hb[N*64 u32] | bsum[1024] |
    //          mat[nb*NBLK] | binned[E u32]   (fallback: cursor = mat slot)
    int* deg    = (int*)d_ws;
    int* offs   = deg + n_nodes;
    int* esrc   = offs + n_nodes;
    unsigned* hb = (unsigned*)(esrc + n_edges);
    int* bsum   = (int*)(hb + (size_t)n_nodes * 64);
    int* mat    = bsum + 1024;
    unsigned* binned = (unsigned*)(mat + (size_t)len);
    int* cursor = mat;

    size_t need_common = ((size_t)2 * n_nodes + (size_t)n_edges + 1024) * sizeof(int)
                       + (size_t)n_nodes * 64 * sizeof(unsigned);
    size_t need_new  = need_common + ((size_t)len + (size_t)n_edges) * sizeof(int);
    size_t need_fall = need_common + (size_t)n_nodes * sizeof(int);
    bool use_new = shift_ok && ws_size >= need_new;

    const int gb = (n_nodes + 63) / 64;

    if (use_new) {
        k_gemm_hist<<<NBLK + gb, 256, 0, stream>>>(h, weight, hb, dst, mat,
                                                   n_nodes, n_edges, nb, NBLK);
        k_scan_a<<<nscan, SCANB, 0, stream>>>(mat, mat, bsum, len);
        k_scan_b<<<1, 512, 0, stream>>>(bsum, nscan);
        const int epb = (n_edges + NBLK - 1) / NBLK;
        k_part_scatter<<<NBLK, 512, 0, stream>>>(src, dst, mat, bsum, binned,
                                                 n_edges, nb, epb);
        k_bin_to_csr<<<nb, 256, 0, stream>>>(binned, mat, bsum, deg, offs, esrc,
                                             n_edges, n_nodes, nb);
        int gblocks = (int)(((size_t)n_nodes * 64 + 255) / 256);
        k_gather_ln<<<gblocks, 256, 0, stream>>>(hb, esrc, offs, deg,
                                                 bias, gamma, beta, x, n_nodes);
    } else if (ws_size >= need_fall) {
        k_gemm_hist<<<gb, 256, 0, stream>>>(h, weight, hb, dst, mat,
                                            n_nodes, n_edges, nb, 0);
        const int nscan2 = (n_nodes + SCANB - 1) / SCANB;
        hipMemsetAsync(deg, 0, (size_t)n_nodes * sizeof(int), stream);
        hipMemsetAsync(cursor, 0, (size_t)n_nodes * sizeof(int), stream);
        k_hist<<<(n_edges + 255) / 256, 256, 0, stream>>>(dst, deg, n_edges);
        k_scan_a<<<nscan2, SCANB, 0, stream>>>(deg, offs, bsum, n_nodes);
        k_scan_b<<<1, 512, 0, stream>>>(bsum, nscan2);
        k_scan_c<<<nscan2, SCANB, 0, stream>>>(offs, bsum, n_nodes);
        k_scatter_idx<<<(n_edges + 255) / 256, 256, 0, stream>>>(
            src, dst, offs, cursor, esrc, n_edges);
        int gblocks = (int)(((size_t)n_nodes * 64 + 255) / 256);
        k_gather_ln<<<gblocks, 256, 0, stream>>>(hb, esrc, offs, deg,
                                                 bias, gamma, beta, x, n_nodes);
    }
}

// Round 16
// 128.994 us; speedup vs baseline: 1.2087x; 1.0044x over previous
//
#include <hip/hip_runtime.h>
#include <hip/hip_fp16.h>

#define F 128
#define SCANB 1024
#define NBLK 256        // hist/scatter block count == mat columns
#define GB2 512         // GEMM blocks in D1 (grid-stride over 64-row tiles)
#define BSHIFT 7        // 128 nodes per bucket
#define MAXNB 2048      // nb guard (lbase capacity; nscan<=512)
#define SMEM_BYTES 43264  // wt(34816) + xs[4][4][132](8448)

typedef __attribute__((ext_vector_type(8))) short short8;
typedef __attribute__((ext_vector_type(4))) float f32x4;

static __device__ __forceinline__ short f2bf(float f) {
    union { float f; unsigned u; } v; v.f = f;
    unsigned r = v.u + 0x7FFF + ((v.u >> 16) & 1);   // round-to-nearest-even
    return (short)(r >> 16);
}
static __device__ __forceinline__ __half2 h2(unsigned u) {
    return __builtin_bit_cast(__half2, u);
}
static __device__ __forceinline__ uint4 pack8h(float a0,float a1,float a2,float a3,
                                               float a4,float a5,float a6,float a7) {
    uint4 o;
    o.x = __builtin_bit_cast(unsigned, __floats2half2_rn(a0, a1));
    o.y = __builtin_bit_cast(unsigned, __floats2half2_rn(a2, a3));
    o.z = __builtin_bit_cast(unsigned, __floats2half2_rn(a4, a5));
    o.w = __builtin_bit_cast(unsigned, __floats2half2_rn(a6, a7));
    return o;
}

// ========== D1: blocks<hblk do dst-hist, rest grid-stride hW GEMM ==========
__global__ __launch_bounds__(256) void k_gemm_hist(
    const float* __restrict__ h, const float* __restrict__ w,
    unsigned* __restrict__ hb, const int* __restrict__ dst,
    int* __restrict__ mat, int* __restrict__ done,
    int n_nodes, int n_edges, int nb, int hblk) {
    __shared__ alignas(16) char smem[SMEM_BYTES];
    const int tid = threadIdx.x;
    const int bid = blockIdx.x;

    if (bid == 0 && tid == 0 && done) *done = 0;   // reset scan ticket

    if (bid < hblk) {
        // ---- histogram role: column bid of mat ----
        int* lh = (int*)smem;
        for (int i = tid; i < nb; i += 256) lh[i] = 0;
        __syncthreads();
        const int epb = (n_edges + hblk - 1) / hblk;
        const int e0 = bid * epb, e1 = min(e0 + epb, n_edges);
        for (int e = e0 + tid; e < e1; e += 256)
            atomicAdd(&lh[dst[e] >> BSHIFT], 1);
        __syncthreads();
        for (int i = tid; i < nb; i += 256)
            mat[(size_t)i * NBLK + bid] = lh[i];
        return;
    }

    // ---- GEMM role: W staged once, grid-stride over 64-row tiles ----
    short* wt = (short*)smem;               // [128*136] bf16 W^T  (34816 B)
    float* xs = (float*)(smem + 34816);     // [4][4][132] per-wave C bounce
    {
        int n = tid & 127;
        for (int k = tid >> 7; k < 128; k += 2)
            wt[n * 136 + k] = f2bf(w[(size_t)k * 128 + n]);
    }
    __syncthreads();

    const int wv = tid >> 6, l = tid & 63, lr = l & 15, lk = l >> 4, q = l & 15;
    const int step = (gridDim.x - hblk) * 64;
    float* xw = xs + wv * (4 * 132);

    for (int base = (bid - hblk) * 64; base < n_nodes; base += step) {
        const int row = base + wv * 16 + lr;
        const bool valid = row < n_nodes;

        short8 af[4];
        #pragma unroll
        for (int kk = 0; kk < 4; ++kk) {
            int k0 = kk * 32 + lk * 8;
            float4 a0{0,0,0,0}, a1{0,0,0,0};
            if (valid) {
                a0 = *(const float4*)(h + (size_t)row * F + k0);
                a1 = *(const float4*)(h + (size_t)row * F + k0 + 4);
            }
            af[kk] = short8{ f2bf(a0.x), f2bf(a0.y), f2bf(a0.z), f2bf(a0.w),
                             f2bf(a1.x), f2bf(a1.y), f2bf(a1.z), f2bf(a1.w) };
        }
        f32x4 acc[8];
        #pragma unroll
        for (int n = 0; n < 8; ++n) acc[n] = f32x4{0, 0, 0, 0};
        #pragma unroll
        for (int kk = 0; kk < 4; ++kk) {
            const int kb = kk * 32 + lk * 8;
            #pragma unroll
            for (int n = 0; n < 8; ++n) {
                short8 bfr = *(const short8*)(&wt[(n * 16 + lr) * 136 + kb]);
                acc[n] = __builtin_amdgcn_mfma_f32_16x16x32_bf16(af[kk], bfr, acc[n], 0, 0, 0);
            }
        }
        // per-r bounce: wave-local region, wave-synchronous reuse
        #pragma unroll
        for (int r = 0; r < 4; ++r) {
            #pragma unroll
            for (int n = 0; n < 8; ++n)
                xw[lk * 132 + n * 16 + lr] = acc[n][r];
            int grow = base + wv * 16 + lk * 4 + r;
            float4 a = *(const float4*)&xw[lk * 132 + q * 8];
            float4 b = *(const float4*)&xw[lk * 132 + q * 8 + 4];
            uint4 o = pack8h(a.x, a.y, a.z, a.w, b.x, b.y, b.z, b.w);
            if (grow < n_nodes)
                ((uint4*)hb)[(size_t)grow * 16 + q] = o;
        }
    }
}

// ========== fused scan: per-chunk scan + last-block scans bsum =============
__global__ __launch_bounds__(SCANB) void k_scan_ab(const int* in, int* out,
                                                   int* bsum, int* done, int n) {
    __shared__ int tmp[SCANB];
    __shared__ bool amLast;
    int i = blockIdx.x * SCANB + threadIdx.x;
    int v = (i < n) ? in[i] : 0;
    tmp[threadIdx.x] = v;
    __syncthreads();
    for (int off = 1; off < SCANB; off <<= 1) {
        int t = (threadIdx.x >= off) ? tmp[threadIdx.x - off] : 0;
        __syncthreads();
        tmp[threadIdx.x] += t;
        __syncthreads();
    }
    if (i < n) out[i] = tmp[threadIdx.x] - v;
    if (threadIdx.x == SCANB - 1) {
        bsum[blockIdx.x] = tmp[SCANB - 1];
        __threadfence();
        int old = atomicAdd(done, 1);
        amLast = (old == (int)gridDim.x - 1);
    }
    __syncthreads();
    if (amLast) {
        __threadfence();
        const int ns = gridDim.x;
        int w = (threadIdx.x < ns) ? ((volatile int*)bsum)[threadIdx.x] : 0;
        __syncthreads();
        tmp[threadIdx.x] = w;
        __syncthreads();
        for (int off = 1; off < SCANB; off <<= 1) {
            int t = (threadIdx.x >= off) ? tmp[threadIdx.x - off] : 0;
            __syncthreads();
            tmp[threadIdx.x] += t;
            __syncthreads();
        }
        if (threadIdx.x < ns) bsum[threadIdx.x] = tmp[threadIdx.x] - w;
    }
}

// ========== classic scan pieces (fallback path) ============================
__global__ __launch_bounds__(SCANB) void k_scan_a(const int* in, int* out,
                                                  int* bsum, int n) {
    __shared__ int tmp[SCANB];
    int i = blockIdx.x * SCANB + threadIdx.x;
    int v = (i < n) ? in[i] : 0;
    tmp[threadIdx.x] = v;
    __syncthreads();
    for (int off = 1; off < SCANB; off <<= 1) {
        int t = (threadIdx.x >= off) ? tmp[threadIdx.x - off] : 0;
        __syncthreads();
        tmp[threadIdx.x] += t;
        __syncthreads();
    }
    if (i < n) out[i] = tmp[threadIdx.x] - v;
    if (threadIdx.x == SCANB - 1) bsum[blockIdx.x] = tmp[SCANB - 1];
}

__global__ __launch_bounds__(512) void k_scan_b(int* bsum, int nb) {
    __shared__ int tmp[512];
    int i = threadIdx.x;
    int v = (i < nb) ? bsum[i] : 0;
    tmp[i] = v;
    __syncthreads();
    for (int off = 1; off < 512; off <<= 1) {
        int t = (i >= off) ? tmp[i - off] : 0;
        __syncthreads();
        tmp[i] += t;
        __syncthreads();
    }
    if (i < nb) bsum[i] = tmp[i] - v;
}

__global__ __launch_bounds__(SCANB) void k_scan_c(int* out, const int* bsum, int n) {
    int i = blockIdx.x * SCANB + threadIdx.x;
    if (i < n) out[i] += bsum[blockIdx.x];
}

// ========== binned scatter (512 thr); scan_c folded via bsum ===============
__global__ __launch_bounds__(512) void k_part_scatter(
    const int* __restrict__ src, const int* __restrict__ dst,
    const int* __restrict__ mat, const int* __restrict__ bsum,
    unsigned* __restrict__ binned, int n_edges, int nb, int epb) {
    __shared__ int lbase[MAXNB];
    const int bid = blockIdx.x;
    for (int i = threadIdx.x; i < nb; i += 512) {
        int idx = i * NBLK + bid;
        lbase[i] = mat[idx] + bsum[idx >> 10];
    }
    __syncthreads();
    int e0 = bid * epb;
    int e1 = min(e0 + epb, n_edges);
    for (int e = e0 + threadIdx.x; e < e1; e += 512) {
        int d = dst[e];
        int b = d >> BSHIFT;
        int pos = atomicAdd(&lbase[b], 1);   // LDS atomic only
        binned[pos] = ((unsigned)(d & ((1 << BSHIFT) - 1)) << 25) | (unsigned)src[e];
    }
}

// ========== per-bucket CSR finalize (512 thr); scan_c folded ===============
__global__ __launch_bounds__(512) void k_bin_to_csr(
    const unsigned* __restrict__ binned, const int* __restrict__ mat,
    const int* __restrict__ bsum, int* __restrict__ deg, int* __restrict__ offs,
    int* __restrict__ esrc, int n_edges, int n_nodes, int nb) {
    __shared__ int ldeg[128], loffs[128], lcur[128];
    int b = blockIdx.x;
    int i0 = b * NBLK;
    int start = mat[i0] + bsum[i0 >> 10];
    int end = n_edges;
    if (b + 1 < nb) {
        int i1 = (b + 1) * NBLK;
        end = mat[i1] + bsum[i1 >> 10];
    }
    int cnt = end - start;
    int base_node = b << BSHIFT;
    int nn = min(1 << BSHIFT, n_nodes - base_node);
    for (int i = threadIdx.x; i < nn; i += 512) { ldeg[i] = 0; lcur[i] = 0; }
    __syncthreads();
    for (int i = threadIdx.x; i < cnt; i += 512)
        atomicAdd(&ldeg[binned[start + i] >> 25], 1);
    __syncthreads();
    if (threadIdx.x == 0) {
        int run = 0;
        for (int i = 0; i < nn; ++i) { loffs[i] = run; run += ldeg[i]; }
    }
    __syncthreads();
    for (int i = threadIdx.x; i < nn; i += 512) {
        deg[base_node + i]  = ldeg[i];
        offs[base_node + i] = start + loffs[i];
    }
    for (int i = threadIdx.x; i < cnt; i += 512) {
        unsigned p = binned[start + i];
        int ln = p >> 25;
        int pos = start + loffs[ln] + atomicAdd(&lcur[ln], 1);  // LDS atomic
        esrc[pos] = (int)(p & ((1u << 25) - 1));
    }
}

// ========== fallback CSR build (direct, node-level scan) ===================
__global__ __launch_bounds__(256) void k_hist(const int* __restrict__ dst,
                                              int* __restrict__ deg, int n_edges) {
    int e = blockIdx.x * 256 + threadIdx.x;
    if (e < n_edges) atomicAdd(&deg[dst[e]], 1);
}

__global__ __launch_bounds__(256) void k_scatter_idx(
    const int* __restrict__ src, const int* __restrict__ dst,
    const int* __restrict__ offs, int* __restrict__ cursor,
    int* __restrict__ esrc, int n_edges) {
    int e = blockIdx.x * 256 + threadIdx.x;
    if (e >= n_edges) return;
    int d = dst[e];
    int pos = offs[d] + atomicAdd(&cursor[d], 1);
    esrc[pos] = src[e];
}

// ========== gather hW rows (f16) + norm + bias + LayerNorm + ReLU ==========
__global__ __launch_bounds__(256) void k_gather_ln(
    const unsigned* __restrict__ hb, const int* __restrict__ esrc,
    const int* __restrict__ offs, const int* __restrict__ deg,
    const float* __restrict__ bias, const float* __restrict__ gamma,
    const float* __restrict__ beta, float* __restrict__ out, int n_nodes) {
    int t = blockIdx.x * 256 + threadIdx.x;
    int node = t >> 6;
    int l = t & 63;
    if (node >= n_nodes) return;
    const int g = l >> 4;
    const int q = l & 15;

    const int start = offs[node];
    const int dn = deg[node];
    const int end = start + dn;

    __half2 c0 = __floats2half2_rn(0.f, 0.f);
    __half2 c1 = c0, c2 = c0, c3 = c0;
    int i = start;
    for (; i + 16 <= end; i += 16) {
        int s0 = esrc[i + g];
        int s1 = esrc[i + 4 + g];
        int s2 = esrc[i + 8 + g];
        int s3 = esrc[i + 12 + g];
        uint4 v0 = *((const uint4*)(hb + (size_t)s0 * 64 + q * 4));
        uint4 v1 = *((const uint4*)(hb + (size_t)s1 * 64 + q * 4));
        uint4 v2 = *((const uint4*)(hb + (size_t)s2 * 64 + q * 4));
        uint4 v3 = *((const uint4*)(hb + (size_t)s3 * 64 + q * 4));
        c0 = __hadd2(c0, __hadd2(__hadd2(h2(v0.x), h2(v1.x)), __hadd2(h2(v2.x), h2(v3.x))));
        c1 = __hadd2(c1, __hadd2(__hadd2(h2(v0.y), h2(v1.y)), __hadd2(h2(v2.y), h2(v3.y))));
        c2 = __hadd2(c2, __hadd2(__hadd2(h2(v0.z), h2(v1.z)), __hadd2(h2(v2.z), h2(v3.z))));
        c3 = __hadd2(c3, __hadd2(__hadd2(h2(v0.w), h2(v1.w)), __hadd2(h2(v2.w), h2(v3.w))));
    }
    for (; i + 8 <= end; i += 8) {
        int s0 = esrc[i + g];
        int s1 = esrc[i + 4 + g];
        uint4 v0 = *((const uint4*)(hb + (size_t)s0 * 64 + q * 4));
        uint4 v1 = *((const uint4*)(hb + (size_t)s1 * 64 + q * 4));
        c0 = __hadd2(c0, __hadd2(h2(v0.x), h2(v1.x)));
        c1 = __hadd2(c1, __hadd2(h2(v0.y), h2(v1.y)));
        c2 = __hadd2(c2, __hadd2(h2(v0.z), h2(v1.z)));
        c3 = __hadd2(c3, __hadd2(h2(v0.w), h2(v1.w)));
    }
    for (; i < end; i += 4) {
        int e = i + g;
        if (e < end) {
            int s = esrc[e];
            uint4 v = *((const uint4*)(hb + (size_t)s * 64 + q * 4));
            c0 = __hadd2(c0, h2(v.x));
            c1 = __hadd2(c1, h2(v.y));
            c2 = __hadd2(c2, h2(v.z));
            c3 = __hadd2(c3, h2(v.w));
        }
    }
    float2 p0 = __half22float2(c0), p1 = __half22float2(c1);
    float2 p2 = __half22float2(c2), p3 = __half22float2(c3);
    float a0 = p0.x, a1 = p0.y, a2 = p1.x, a3 = p1.y;
    float a4 = p2.x, a5 = p2.y, a6 = p3.x, a7 = p3.y;

    #pragma unroll
    for (int m = 16; m <= 32; m <<= 1) {
        a0 += __shfl_xor(a0, m); a1 += __shfl_xor(a1, m);
        a2 += __shfl_xor(a2, m); a3 += __shfl_xor(a3, m);
        a4 += __shfl_xor(a4, m); a5 += __shfl_xor(a5, m);
        a6 += __shfl_xor(a6, m); a7 += __shfl_xor(a7, m);
    }
    float4 bs0 = *(const float4*)(bias  + q * 8);
    float4 bs1 = *(const float4*)(bias  + q * 8 + 4);
    const float nv = dn > 0 ? 1.0f / (float)dn : 0.0f;
    float f0 = a0 * nv + bs0.x, f1 = a1 * nv + bs0.y;
    float f2 = a2 * nv + bs0.z, f3 = a3 * nv + bs0.w;
    float f4 = a4 * nv + bs1.x, f5 = a5 * nv + bs1.y;
    float f6 = a6 * nv + bs1.z, f7 = a7 * nv + bs1.w;

    float s  = ((f0 + f1) + (f2 + f3)) + ((f4 + f5) + (f6 + f7));
    float q2 = ((f0*f0 + f1*f1) + (f2*f2 + f3*f3)) + ((f4*f4 + f5*f5) + (f6*f6 + f7*f7));
    #pragma unroll
    for (int m = 1; m <= 8; m <<= 1) {
        s  += __shfl_xor(s, m);
        q2 += __shfl_xor(q2, m);
    }
    float mu   = s * (1.0f / F);
    float var  = q2 * (1.0f / F) - mu * mu;
    float rstd = rsqrtf(var + 1e-5f);

    if (g == 0) {
        float4 gm0 = *(const float4*)(gamma + q * 8);
        float4 gm1 = *(const float4*)(gamma + q * 8 + 4);
        float4 bt0 = *(const float4*)(beta  + q * 8);
        float4 bt1 = *(const float4*)(beta  + q * 8 + 4);
        float4 o0, o1;
        o0.x = fmaxf((f0 - mu) * rstd * gm0.x + bt0.x, 0.0f);
        o0.y = fmaxf((f1 - mu) * rstd * gm0.y + bt0.y, 0.0f);
        o0.z = fmaxf((f2 - mu) * rstd * gm0.z + bt0.z, 0.0f);
        o0.w = fmaxf((f3 - mu) * rstd * gm0.w + bt0.w, 0.0f);
        o1.x = fmaxf((f4 - mu) * rstd * gm1.x + bt1.x, 0.0f);
        o1.y = fmaxf((f5 - mu) * rstd * gm1.y + bt1.y, 0.0f);
        o1.z = fmaxf((f6 - mu) * rstd * gm1.z + bt1.z, 0.0f);
        o1.w = fmaxf((f7 - mu) * rstd * gm1.w + bt1.w, 0.0f);
        float* op = out + (size_t)node * F + q * 8;
        *(float4*)op = o0;
        *(float4*)(op + 4) = o1;
    }
}

extern "C" void kernel_launch(void* const* d_in, const int* in_sizes, int n_in,
                              void* d_out, int out_size, void* d_ws, size_t ws_size,
                              hipStream_t stream) {
    const float* h      = (const float*)d_in[0];
    const float* weight = (const float*)d_in[1];
    const float* bias   = (const float*)d_in[2];
    const float* gamma  = (const float*)d_in[3];
    const float* beta   = (const float*)d_in[4];
    const int*   src    = (const int*)d_in[5];
    const int*   dst    = (const int*)d_in[6];

    const int n_nodes = in_sizes[0] / F;
    const int n_edges = in_sizes[5];

    float* x = (float*)d_out;

    const int nb = (n_nodes + (1 << BSHIFT) - 1) >> BSHIFT;
    const int len = nb * NBLK;
    const int nscan = (len + SCANB - 1) / SCANB;
    const bool shift_ok = (nb <= MAXNB) && (nscan <= 512) && (n_nodes <= (1 << 25));

    // ws ints: deg[N] | offs[N] | esrc[E] | hb[N*64 u32] | bsum[1023]+done[1] |
    //          mat[nb*NBLK] | binned[E u32]   (fallback: cursor = mat slot)
    int* deg    = (int*)d_ws;
    int* offs   = deg + n_nodes;
    int* esrc   = offs + n_nodes;
    unsigned* hb = (unsigned*)(esrc + n_edges);
    int* bsum   = (int*)(hb + (size_t)n_nodes * 64);
    int* done   = bsum + 1023;
    int* mat    = bsum + 1024;
    unsigned* binned = (unsigned*)(mat + (size_t)len);
    int* cursor = mat;

    size_t need_common = ((size_t)2 * n_nodes + (size_t)n_edges + 1024) * sizeof(int)
                       + (size_t)n_nodes * 64 * sizeof(unsigned);
    size_t need_new  = need_common + ((size_t)len + (size_t)n_edges) * sizeof(int);
    size_t need_fall = need_common + (size_t)n_nodes * sizeof(int);
    bool use_new = shift_ok && ws_size >= need_new;

    const int gb = (n_nodes + 63) / 64;

    if (use_new) {
        k_gemm_hist<<<NBLK + GB2, 256, 0, stream>>>(h, weight, hb, dst, mat, done,
                                                    n_nodes, n_edges, nb, NBLK);
        k_scan_ab<<<nscan, SCANB, 0, stream>>>(mat, mat, bsum, done, len);
        const int epb = (n_edges + NBLK - 1) / NBLK;
        k_part_scatter<<<NBLK, 512, 0, stream>>>(src, dst, mat, bsum, binned,
                                                 n_edges, nb, epb);
        k_bin_to_csr<<<nb, 512, 0, stream>>>(binned, mat, bsum, deg, offs, esrc,
                                             n_edges, n_nodes, nb);
        int gblocks = (int)(((size_t)n_nodes * 64 + 255) / 256);
        k_gather_ln<<<gblocks, 256, 0, stream>>>(hb, esrc, offs, deg,
                                                 bias, gamma, beta, x, n_nodes);
    } else if (ws_size >= need_fall) {
        k_gemm_hist<<<gb, 256, 0, stream>>>(h, weight, hb, dst, mat, (int*)nullptr,
                                            n_nodes, n_edges, nb, 0);
        const int nscan2 = (n_nodes + SCANB - 1) / SCANB;
        hipMemsetAsync(deg, 0, (size_t)n_nodes * sizeof(int), stream);
        hipMemsetAsync(cursor, 0, (size_t)n_nodes * sizeof(int), stream);
        k_hist<<<(n_edges + 255) / 256, 256, 0, stream>>>(dst, deg, n_edges);
        k_scan_a<<<nscan2, SCANB, 0, stream>>>(deg, offs, bsum, n_nodes);
        k_scan_b<<<1, 512, 0, stream>>>(bsum, nscan2);
        k_scan_c<<<nscan2, SCANB, 0, stream>>>(offs, bsum, n_nodes);
        k_scatter_idx<<<(n_edges + 255) / 256, 256, 0, stream>>>(
            src, dst, offs, cursor, esrc, n_edges);
        int gblocks = (int)(((size_t)n_nodes * 64 + 255) / 256);
        k_gather_ln<<<gblocks, 256, 0, stream>>>(hb, esrc, offs, deg,
                                                 bias, gamma, beta, x, n_nodes);
    }
}

// Round 17
// 123.916 us; speedup vs baseline: 1.2583x; 1.0410x over previous
//
#include <hip/hip_runtime.h>
#include <hip/hip_fp16.h>

#define F 128
#define SCANB 1024
#define NBLK 256        // hist/scatter block count == mat columns
#define GB2 512         // GEMM blocks in D1 (grid-stride over 64-row tiles)
#define BSHIFT 9        // 512 nodes per bucket (128B scatter runs)
#define BS (1 << BSHIFT)
#define PSH 23          // pack shift: 9-bit local dst | 23-bit src
#define MAXNB 2048      // lbase capacity guard
#define SMEM_BYTES 43264  // wt(34816) + xs[4][4][132](8448)

typedef __attribute__((ext_vector_type(8))) short short8;
typedef __attribute__((ext_vector_type(4))) float f32x4;

static __device__ __forceinline__ short f2bf(float f) {
    union { float f; unsigned u; } v; v.f = f;
    unsigned r = v.u + 0x7FFF + ((v.u >> 16) & 1);   // round-to-nearest-even
    return (short)(r >> 16);
}
static __device__ __forceinline__ __half2 h2(unsigned u) {
    return __builtin_bit_cast(__half2, u);
}
static __device__ __forceinline__ uint4 pack8h(float a0,float a1,float a2,float a3,
                                               float a4,float a5,float a6,float a7) {
    uint4 o;
    o.x = __builtin_bit_cast(unsigned, __floats2half2_rn(a0, a1));
    o.y = __builtin_bit_cast(unsigned, __floats2half2_rn(a2, a3));
    o.z = __builtin_bit_cast(unsigned, __floats2half2_rn(a4, a5));
    o.w = __builtin_bit_cast(unsigned, __floats2half2_rn(a6, a7));
    return o;
}

// ========== D1: blocks<hblk do dst-hist, rest grid-stride hW GEMM ==========
__global__ __launch_bounds__(256) void k_gemm_hist(
    const float* __restrict__ h, const float* __restrict__ w,
    unsigned* __restrict__ hb, const int* __restrict__ dst,
    int* __restrict__ mat, int* __restrict__ done,
    int n_nodes, int n_edges, int nb, int hblk) {
    __shared__ alignas(16) char smem[SMEM_BYTES];
    const int tid = threadIdx.x;
    const int bid = blockIdx.x;

    if (bid == 0 && tid == 0 && done) *done = 0;   // reset scan ticket

    if (bid < hblk) {
        // ---- histogram role: column bid of mat ----
        int* lh = (int*)smem;
        for (int i = tid; i < nb; i += 256) lh[i] = 0;
        __syncthreads();
        const int epb = (n_edges + hblk - 1) / hblk;
        const int e0 = bid * epb, e1 = min(e0 + epb, n_edges);
        for (int e = e0 + tid; e < e1; e += 256)
            atomicAdd(&lh[dst[e] >> BSHIFT], 1);
        __syncthreads();
        for (int i = tid; i < nb; i += 256)
            mat[(size_t)i * NBLK + bid] = lh[i];
        return;
    }

    // ---- GEMM role: W staged once, grid-stride over 64-row tiles ----
    short* wt = (short*)smem;               // [128*136] bf16 W^T  (34816 B)
    float* xs = (float*)(smem + 34816);     // [4][4][132] per-wave C bounce
    {
        int n = tid & 127;
        for (int k = tid >> 7; k < 128; k += 2)
            wt[n * 136 + k] = f2bf(w[(size_t)k * 128 + n]);
    }
    __syncthreads();

    const int wv = tid >> 6, l = tid & 63, lr = l & 15, lk = l >> 4, q = l & 15;
    const int step = (gridDim.x - hblk) * 64;
    float* xw = xs + wv * (4 * 132);

    for (int base = (bid - hblk) * 64; base < n_nodes; base += step) {
        const int row = base + wv * 16 + lr;
        const bool valid = row < n_nodes;

        short8 af[4];
        #pragma unroll
        for (int kk = 0; kk < 4; ++kk) {
            int k0 = kk * 32 + lk * 8;
            float4 a0{0,0,0,0}, a1{0,0,0,0};
            if (valid) {
                a0 = *(const float4*)(h + (size_t)row * F + k0);
                a1 = *(const float4*)(h + (size_t)row * F + k0 + 4);
            }
            af[kk] = short8{ f2bf(a0.x), f2bf(a0.y), f2bf(a0.z), f2bf(a0.w),
                             f2bf(a1.x), f2bf(a1.y), f2bf(a1.z), f2bf(a1.w) };
        }
        f32x4 acc[8];
        #pragma unroll
        for (int n = 0; n < 8; ++n) acc[n] = f32x4{0, 0, 0, 0};
        #pragma unroll
        for (int kk = 0; kk < 4; ++kk) {
            const int kb = kk * 32 + lk * 8;
            #pragma unroll
            for (int n = 0; n < 8; ++n) {
                short8 bfr = *(const short8*)(&wt[(n * 16 + lr) * 136 + kb]);
                acc[n] = __builtin_amdgcn_mfma_f32_16x16x32_bf16(af[kk], bfr, acc[n], 0, 0, 0);
            }
        }
        #pragma unroll
        for (int r = 0; r < 4; ++r) {
            #pragma unroll
            for (int n = 0; n < 8; ++n)
                xw[lk * 132 + n * 16 + lr] = acc[n][r];
            int grow = base + wv * 16 + lk * 4 + r;
            float4 a = *(const float4*)&xw[lk * 132 + q * 8];
            float4 b = *(const float4*)&xw[lk * 132 + q * 8 + 4];
            uint4 o = pack8h(a.x, a.y, a.z, a.w, b.x, b.y, b.z, b.w);
            if (grow < n_nodes)
                ((uint4*)hb)[(size_t)grow * 16 + q] = o;
        }
    }
}

// ========== fused scan: per-chunk scan + last-block scans bsum =============
__global__ __launch_bounds__(SCANB) void k_scan_ab(const int* in, int* out,
                                                   int* bsum, int* done, int n) {
    __shared__ int tmp[SCANB];
    __shared__ bool amLast;
    int i = blockIdx.x * SCANB + threadIdx.x;
    int v = (i < n) ? in[i] : 0;
    tmp[threadIdx.x] = v;
    __syncthreads();
    for (int off = 1; off < SCANB; off <<= 1) {
        int t = (threadIdx.x >= off) ? tmp[threadIdx.x - off] : 0;
        __syncthreads();
        tmp[threadIdx.x] += t;
        __syncthreads();
    }
    if (i < n) out[i] = tmp[threadIdx.x] - v;
    if (threadIdx.x == SCANB - 1) {
        bsum[blockIdx.x] = tmp[SCANB - 1];
        __threadfence();
        int old = atomicAdd(done, 1);
        amLast = (old == (int)gridDim.x - 1);
    }
    __syncthreads();
    if (amLast) {
        __threadfence();
        const int ns = gridDim.x;
        int w = (threadIdx.x < ns) ? ((volatile int*)bsum)[threadIdx.x] : 0;
        __syncthreads();
        tmp[threadIdx.x] = w;
        __syncthreads();
        for (int off = 1; off < SCANB; off <<= 1) {
            int t = (threadIdx.x >= off) ? tmp[threadIdx.x - off] : 0;
            __syncthreads();
            tmp[threadIdx.x] += t;
            __syncthreads();
        }
        if (threadIdx.x < ns) bsum[threadIdx.x] = tmp[threadIdx.x] - w;
    }
}

// ========== classic scan pieces (fallback path) ============================
__global__ __launch_bounds__(SCANB) void k_scan_a(const int* in, int* out,
                                                  int* bsum, int n) {
    __shared__ int tmp[SCANB];
    int i = blockIdx.x * SCANB + threadIdx.x;
    int v = (i < n) ? in[i] : 0;
    tmp[threadIdx.x] = v;
    __syncthreads();
    for (int off = 1; off < SCANB; off <<= 1) {
        int t = (threadIdx.x >= off) ? tmp[threadIdx.x - off] : 0;
        __syncthreads();
        tmp[threadIdx.x] += t;
        __syncthreads();
    }
    if (i < n) out[i] = tmp[threadIdx.x] - v;
    if (threadIdx.x == SCANB - 1) bsum[blockIdx.x] = tmp[SCANB - 1];
}

__global__ __launch_bounds__(512) void k_scan_b(int* bsum, int nb) {
    __shared__ int tmp[512];
    int i = threadIdx.x;
    int v = (i < nb) ? bsum[i] : 0;
    tmp[i] = v;
    __syncthreads();
    for (int off = 1; off < 512; off <<= 1) {
        int t = (i >= off) ? tmp[i - off] : 0;
        __syncthreads();
        tmp[i] += t;
        __syncthreads();
    }
    if (i < nb) bsum[i] = tmp[i] - v;
}

__global__ __launch_bounds__(SCANB) void k_scan_c(int* out, const int* bsum, int n) {
    int i = blockIdx.x * SCANB + threadIdx.x;
    if (i < n) out[i] += bsum[blockIdx.x];
}

// ========== binned scatter (512 thr); 128B runs per (bucket,block) =========
__global__ __launch_bounds__(512) void k_part_scatter(
    const int* __restrict__ src, const int* __restrict__ dst,
    const int* __restrict__ mat, const int* __restrict__ bsum,
    unsigned* __restrict__ binned, int n_edges, int nb, int epb) {
    __shared__ int lbase[MAXNB];
    const int bid = blockIdx.x;
    for (int i = threadIdx.x; i < nb; i += 512) {
        int idx = i * NBLK + bid;
        lbase[i] = mat[idx] + bsum[idx >> 10];
    }
    __syncthreads();
    int e0 = bid * epb;
    int e1 = min(e0 + epb, n_edges);
    for (int e = e0 + threadIdx.x; e < e1; e += 512) {
        int d = dst[e];
        int b = d >> BSHIFT;
        int pos = atomicAdd(&lbase[b], 1);   // LDS atomic only
        binned[pos] = ((unsigned)(d & (BS - 1)) << PSH) | (unsigned)src[e];
    }
}

// ========== per-bucket CSR finalize (512 thr, parallel local scan) =========
__global__ __launch_bounds__(512) void k_bin_to_csr(
    const unsigned* __restrict__ binned, const int* __restrict__ mat,
    const int* __restrict__ bsum, int* __restrict__ deg, int* __restrict__ offs,
    int* __restrict__ esrc, int n_edges, int n_nodes, int nb) {
    __shared__ int ldeg[BS], loffs[BS], lcur[BS];
    const int tid = threadIdx.x;
    int b = blockIdx.x;
    int i0 = b * NBLK;
    int start = mat[i0] + bsum[i0 >> 10];
    int end = n_edges;
    if (b + 1 < nb) {
        int i1 = (b + 1) * NBLK;
        end = mat[i1] + bsum[i1 >> 10];
    }
    int cnt = end - start;
    int base_node = b << BSHIFT;
    int nn = min(BS, n_nodes - base_node);

    ldeg[tid] = 0; lcur[tid] = 0;
    __syncthreads();
    for (int i = tid; i < cnt; i += 512)
        atomicAdd(&ldeg[binned[start + i] >> PSH], 1);
    __syncthreads();
    // parallel exclusive scan of ldeg -> loffs (Hillis-Steele, 512 wide)
    int v = ldeg[tid];
    loffs[tid] = v;
    __syncthreads();
    for (int off = 1; off < BS; off <<= 1) {
        int t = (tid >= off) ? loffs[tid - off] : 0;
        __syncthreads();
        loffs[tid] += t;
        __syncthreads();
    }
    int excl = loffs[tid] - v;
    __syncthreads();
    loffs[tid] = excl;
    __syncthreads();

    if (tid < nn) {
        deg[base_node + tid]  = ldeg[tid];
        offs[base_node + tid] = start + loffs[tid];
    }
    for (int i = tid; i < cnt; i += 512) {
        unsigned p = binned[start + i];
        int ln = p >> PSH;
        int pos = start + loffs[ln] + atomicAdd(&lcur[ln], 1);  // LDS atomic
        esrc[pos] = (int)(p & ((1u << PSH) - 1));
    }
}

// ========== fallback CSR build (direct, node-level scan) ===================
__global__ __launch_bounds__(256) void k_hist(const int* __restrict__ dst,
                                              int* __restrict__ deg, int n_edges) {
    int e = blockIdx.x * 256 + threadIdx.x;
    if (e < n_edges) atomicAdd(&deg[dst[e]], 1);
}

__global__ __launch_bounds__(256) void k_scatter_idx(
    const int* __restrict__ src, const int* __restrict__ dst,
    const int* __restrict__ offs, int* __restrict__ cursor,
    int* __restrict__ esrc, int n_edges) {
    int e = blockIdx.x * 256 + threadIdx.x;
    if (e >= n_edges) return;
    int d = dst[e];
    int pos = offs[d] + atomicAdd(&cursor[d], 1);
    esrc[pos] = src[e];
}

// ========== gather hW rows (f16) + norm + bias + LayerNorm + ReLU ==========
__global__ __launch_bounds__(256) void k_gather_ln(
    const unsigned* __restrict__ hb, const int* __restrict__ esrc,
    const int* __restrict__ offs, const int* __restrict__ deg,
    const float* __restrict__ bias, const float* __restrict__ gamma,
    const float* __restrict__ beta, float* __restrict__ out, int n_nodes) {
    int t = blockIdx.x * 256 + threadIdx.x;
    int node = t >> 6;
    int l = t & 63;
    if (node >= n_nodes) return;
    const int g = l >> 4;
    const int q = l & 15;

    const int start = offs[node];
    const int dn = deg[node];
    const int end = start + dn;

    __half2 c0 = __floats2half2_rn(0.f, 0.f);
    __half2 c1 = c0, c2 = c0, c3 = c0;
    int i = start;
    for (; i + 16 <= end; i += 16) {
        int s0 = esrc[i + g];
        int s1 = esrc[i + 4 + g];
        int s2 = esrc[i + 8 + g];
        int s3 = esrc[i + 12 + g];
        uint4 v0 = *((const uint4*)(hb + (size_t)s0 * 64 + q * 4));
        uint4 v1 = *((const uint4*)(hb + (size_t)s1 * 64 + q * 4));
        uint4 v2 = *((const uint4*)(hb + (size_t)s2 * 64 + q * 4));
        uint4 v3 = *((const uint4*)(hb + (size_t)s3 * 64 + q * 4));
        c0 = __hadd2(c0, __hadd2(__hadd2(h2(v0.x), h2(v1.x)), __hadd2(h2(v2.x), h2(v3.x))));
        c1 = __hadd2(c1, __hadd2(__hadd2(h2(v0.y), h2(v1.y)), __hadd2(h2(v2.y), h2(v3.y))));
        c2 = __hadd2(c2, __hadd2(__hadd2(h2(v0.z), h2(v1.z)), __hadd2(h2(v2.z), h2(v3.z))));
        c3 = __hadd2(c3, __hadd2(__hadd2(h2(v0.w), h2(v1.w)), __hadd2(h2(v2.w), h2(v3.w))));
    }
    for (; i + 8 <= end; i += 8) {
        int s0 = esrc[i + g];
        int s1 = esrc[i + 4 + g];
        uint4 v0 = *((const uint4*)(hb + (size_t)s0 * 64 + q * 4));
        uint4 v1 = *((const uint4*)(hb + (size_t)s1 * 64 + q * 4));
        c0 = __hadd2(c0, __hadd2(h2(v0.x), h2(v1.x)));
        c1 = __hadd2(c1, __hadd2(h2(v0.y), h2(v1.y)));
        c2 = __hadd2(c2, __hadd2(h2(v0.z), h2(v1.z)));
        c3 = __hadd2(c3, __hadd2(h2(v0.w), h2(v1.w)));
    }
    for (; i < end; i += 4) {
        int e = i + g;
        if (e < end) {
            int s = esrc[e];
            uint4 v = *((const uint4*)(hb + (size_t)s * 64 + q * 4));
            c0 = __hadd2(c0, h2(v.x));
            c1 = __hadd2(c1, h2(v.y));
            c2 = __hadd2(c2, h2(v.z));
            c3 = __hadd2(c3, h2(v.w));
        }
    }
    float2 p0 = __half22float2(c0), p1 = __half22float2(c1);
    float2 p2 = __half22float2(c2), p3 = __half22float2(c3);
    float a0 = p0.x, a1 = p0.y, a2 = p1.x, a3 = p1.y;
    float a4 = p2.x, a5 = p2.y, a6 = p3.x, a7 = p3.y;

    #pragma unroll
    for (int m = 16; m <= 32; m <<= 1) {
        a0 += __shfl_xor(a0, m); a1 += __shfl_xor(a1, m);
        a2 += __shfl_xor(a2, m); a3 += __shfl_xor(a3, m);
        a4 += __shfl_xor(a4, m); a5 += __shfl_xor(a5, m);
        a6 += __shfl_xor(a6, m); a7 += __shfl_xor(a7, m);
    }
    float4 bs0 = *(const float4*)(bias  + q * 8);
    float4 bs1 = *(const float4*)(bias  + q * 8 + 4);
    const float nv = dn > 0 ? 1.0f / (float)dn : 0.0f;
    float f0 = a0 * nv + bs0.x, f1 = a1 * nv + bs0.y;
    float f2 = a2 * nv + bs0.z, f3 = a3 * nv + bs0.w;
    float f4 = a4 * nv + bs1.x, f5 = a5 * nv + bs1.y;
    float f6 = a6 * nv + bs1.z, f7 = a7 * nv + bs1.w;

    float s  = ((f0 + f1) + (f2 + f3)) + ((f4 + f5) + (f6 + f7));
    float q2 = ((f0*f0 + f1*f1) + (f2*f2 + f3*f3)) + ((f4*f4 + f5*f5) + (f6*f6 + f7*f7));
    #pragma unroll
    for (int m = 1; m <= 8; m <<= 1) {
        s  += __shfl_xor(s, m);
        q2 += __shfl_xor(q2, m);
    }
    float mu   = s * (1.0f / F);
    float var  = q2 * (1.0f / F) - mu * mu;
    float rstd = rsqrtf(var + 1e-5f);

    if (g == 0) {
        float4 gm0 = *(const float4*)(gamma + q * 8);
        float4 gm1 = *(const float4*)(gamma + q * 8 + 4);
        float4 bt0 = *(const float4*)(beta  + q * 8);
        float4 bt1 = *(const float4*)(beta  + q * 8 + 4);
        float4 o0, o1;
        o0.x = fmaxf((f0 - mu) * rstd * gm0.x + bt0.x, 0.0f);
        o0.y = fmaxf((f1 - mu) * rstd * gm0.y + bt0.y, 0.0f);
        o0.z = fmaxf((f2 - mu) * rstd * gm0.z + bt0.z, 0.0f);
        o0.w = fmaxf((f3 - mu) * rstd * gm0.w + bt0.w, 0.0f);
        o1.x = fmaxf((f4 - mu) * rstd * gm1.x + bt1.x, 0.0f);
        o1.y = fmaxf((f5 - mu) * rstd * gm1.y + bt1.y, 0.0f);
        o1.z = fmaxf((f6 - mu) * rstd * gm1.z + bt1.z, 0.0f);
        o1.w = fmaxf((f7 - mu) * rstd * gm1.w + bt1.w, 0.0f);
        float* op = out + (size_t)node * F + q * 8;
        *(float4*)op = o0;
        *(float4*)(op + 4) = o1;
    }
}

extern "C" void kernel_launch(void* const* d_in, const int* in_sizes, int n_in,
                              void* d_out, int out_size, void* d_ws, size_t ws_size,
                              hipStream_t stream) {
    const float* h      = (const float*)d_in[0];
    const float* weight = (const float*)d_in[1];
    const float* bias   = (const float*)d_in[2];
    const float* gamma  = (const float*)d_in[3];
    const float* beta   = (const float*)d_in[4];
    const int*   src    = (const int*)d_in[5];
    const int*   dst    = (const int*)d_in[6];

    const int n_nodes = in_sizes[0] / F;
    const int n_edges = in_sizes[5];

    float* x = (float*)d_out;

    const int nb = (n_nodes + BS - 1) >> BSHIFT;
    const int len = nb * NBLK;
    const int nscan = (len + SCANB - 1) / SCANB;
    // guards: lbase/scan capacity; pack = 9-bit local dst + 23-bit src
    const bool shift_ok = (nb <= MAXNB) && (nscan <= 512) && (n_nodes <= (1 << PSH));

    // ws ints: deg[N] | offs[N] | esrc[E] | hb[N*64 u32] | bsum[1023]+done[1] |
    //          mat[nb*NBLK] | binned[E u32]   (fallback: cursor = mat slot)
    int* deg    = (int*)d_ws;
    int* offs   = deg + n_nodes;
    int* esrc   = offs + n_nodes;
    unsigned* hb = (unsigned*)(esrc + n_edges);
    int* bsum   = (int*)(hb + (size_t)n_nodes * 64);
    int* done   = bsum + 1023;
    int* mat    = bsum + 1024;
    unsigned* binned = (unsigned*)(mat + (size_t)len);
    int* cursor = mat;

    size_t need_common = ((size_t)2 * n_nodes + (size_t)n_edges + 1024) * sizeof(int)
                       + (size_t)n_nodes * 64 * sizeof(unsigned);
    size_t need_new  = need_common + ((size_t)len + (size_t)n_edges) * sizeof(int);
    size_t need_fall = need_common + (size_t)n_nodes * sizeof(int);
    bool use_new = shift_ok && ws_size >= need_new;

    const int gb = (n_nodes + 63) / 64;

    if (use_new) {
        k_gemm_hist<<<NBLK + GB2, 256, 0, stream>>>(h, weight, hb, dst, mat, done,
                                                    n_nodes, n_edges, nb, NBLK);
        k_scan_ab<<<nscan, SCANB, 0, stream>>>(mat, mat, bsum, done, len);
        const int epb = (n_edges + NBLK - 1) / NBLK;
        k_part_scatter<<<NBLK, 512, 0, stream>>>(src, dst, mat, bsum, binned,
                                                 n_edges, nb, epb);
        k_bin_to_csr<<<nb, 512, 0, stream>>>(binned, mat, bsum, deg, offs, esrc,
                                             n_edges, n_nodes, nb);
        int gblocks = (int)(((size_t)n_nodes * 64 + 255) / 256);
        k_gather_ln<<<gblocks, 256, 0, stream>>>(hb, esrc, offs, deg,
                                                 bias, gamma, beta, x, n_nodes);
    } else if (ws_size >= need_fall) {
        k_gemm_hist<<<gb, 256, 0, stream>>>(h, weight, hb, dst, mat, (int*)nullptr,
                                            n_nodes, n_edges, nb, 0);
        const int nscan2 = (n_nodes + SCANB - 1) / SCANB;
        hipMemsetAsync(deg, 0, (size_t)n_nodes * sizeof(int), stream);
        hipMemsetAsync(cursor, 0, (size_t)n_nodes * sizeof(int), stream);
        k_hist<<<(n_edges + 255) / 256, 256, 0, stream>>>(dst, deg, n_edges);
        k_scan_a<<<nscan2, SCANB, 0, stream>>>(deg, offs, bsum, n_nodes);
        k_scan_b<<<1, 512, 0, stream>>>(bsum, nscan2);
        k_scan_c<<<nscan2, SCANB, 0, stream>>>(offs, bsum, n_nodes);
        k_scatter_idx<<<(n_edges + 255) / 256, 256, 0, stream>>>(
            src, dst, offs, cursor, esrc, n_edges);
        int gblocks = (int)(((size_t)n_nodes * 64 + 255) / 256);
        k_gather_ln<<<gblocks, 256, 0, stream>>>(hb, esrc, offs, deg,
                                                 bias, gamma, beta, x, n_nodes);
    }
}